// Round 1
// baseline (2211.588 us; speedup 1.0000x reference)
//
#include <hip/hip_runtime.h>
#include <hip/hip_bf16.h>

using bf16 = __hip_bfloat16;

constexpr int B = 16, N = 256, D = 128, H = 8, G = 64;
constexpr int SW = N + G;          // 320
constexpr int NITER = 4;
constexpr float FNEG = -1000000000.0f;

__device__ __forceinline__ float b2f(bf16 v) { return __bfloat162float(v); }
__device__ __forceinline__ bf16  f2b(float v) { return __float2bfloat16(v); }

// ---------------- qz = softmax(Q, axis=-1), rows of length D=128 -------------
__global__ __launch_bounds__(64) void k_softmax_qz(const float* __restrict__ Q,
                                                   float* __restrict__ qz) {
  const int row = blockIdx.x;           // b*N + i
  const int lane = threadIdx.x;         // 0..63
  const float* q = Q + (size_t)row * D;
  float v0 = q[lane], v1 = q[lane + 64];
  float m = fmaxf(v0, v1);
  #pragma unroll
  for (int off = 32; off; off >>= 1) m = fmaxf(m, __shfl_xor(m, off));
  float e0 = __expf(v0 - m), e1 = __expf(v1 - m);
  float s = e0 + e1;
  #pragma unroll
  for (int off = 32; off; off >>= 1) s += __shfl_xor(s, off);
  float inv = 1.0f / s;
  float* o = qz + (size_t)row * D;
  o[lane] = e0 * inv;
  o[lane + 64] = e1 * inv;
}

// ---------------- out = x (residual base) -----------------------------------
__global__ __launch_bounds__(256) void k_init(const float* __restrict__ x,
                                              float* __restrict__ out) {
  const int idx = blockIdx.x * 256 + threadIdx.x;
  ((float4*)out)[idx] = ((const float4*)x)[idx];
}

// ---------------- left/right projections -------------------------------------
// left [k,h,(b,i),c] = sum_a qz[(b,i),a] * T[k,a,c,h]
// right[k,h,(b,j),a] = sum_c qz[(b,j),c] * T[k,a,c,h]
template <bool RIGHT>
__global__ __launch_bounds__(256) void k_proj(const float* __restrict__ qz,
                                              const float* __restrict__ tern,
                                              bf16* __restrict__ out) {
  const int kh = blockIdx.y;                 // 0..15, k = kh>>3, h = kh&7
  const int k = kh >> 3, h = kh & 7;
  const int r0 = blockIdx.x * 32;            // row in [0, B*N)
  __shared__ float qzT[32][33];              // [row][red-chunk]
  __shared__ float Tt[32][132];              // [red][out-col]
  const int tid = threadIdx.x;
  const int cg = tid & 31, rg = tid >> 5;    // out col = cg*4+x, row = rg*4+y
  float acc[4][4] = {};
  for (int p0 = 0; p0 < D; p0 += 32) {
    {
      int lr = tid >> 3, lp = (tid & 7) * 4;
      float4 v = *(const float4*)(qz + (size_t)(r0 + lr) * D + p0 + lp);
      qzT[lr][lp] = v.x; qzT[lr][lp + 1] = v.y; qzT[lr][lp + 2] = v.z; qzT[lr][lp + 3] = v.w;
    }
    {
      int lp = tid >> 3, lo0 = (tid & 7) * 16;
      if (!RIGHT) {
        const float* tb = tern + (((size_t)k * D + (p0 + lp)) * D + lo0) * H + h;
        #pragma unroll
        for (int q = 0; q < 16; q++) Tt[lp][lo0 + q] = tb[q * H];
      } else {
        const float* tb = tern + (((size_t)k * D + lo0) * D + (p0 + lp)) * H + h;
        #pragma unroll
        for (int q = 0; q < 16; q++) Tt[lp][lo0 + q] = tb[q * D * H];
      }
    }
    __syncthreads();
    for (int p = 0; p < 32; p++) {
      float4 tv = *(const float4*)&Tt[p][cg * 4];
      float qv[4];
      #pragma unroll
      for (int y = 0; y < 4; y++) qv[y] = qzT[rg * 4 + y][p];
      #pragma unroll
      for (int y = 0; y < 4; y++) {
        acc[y][0] += qv[y] * tv.x; acc[y][1] += qv[y] * tv.y;
        acc[y][2] += qv[y] * tv.z; acc[y][3] += qv[y] * tv.w;
      }
    }
    __syncthreads();
  }
  #pragma unroll
  for (int y = 0; y < 4; y++) {
    int r = r0 + rg * 4 + y;
    bf16* dst = out + ((size_t)kh * (B * N) + r) * D + cg * 4;
    #pragma unroll
    for (int x = 0; x < 4; x++) dst[x] = f2b(acc[y][x]);
  }
}

// ---------------- F part of S: S[b,h,i,j] = leftSel(i,j) . qz[b,j,:] + bias ---
__global__ __launch_bounds__(256) void k_F(const float* __restrict__ qz,
                                           const bf16* __restrict__ left,
                                           const int* __restrict__ mask,
                                           float* __restrict__ S) {
  const int b = blockIdx.z, h = blockIdx.y;
  const int i0 = (blockIdx.x & 7) * 32;
  const int j0 = (blockIdx.x >> 3) * 128;
  __shared__ float L0[32][33], L1[32][33];   // [i][c-chunk]
  __shared__ float QT[32][132];              // [c-chunk][j]
  const int tid = threadIdx.x;
  const int jg = tid & 31, ig = tid >> 5;    // j = j0+jg*4+x, i = i0+ig*4+y
  float acc[4][4] = {};
  const bool allUp = (j0 >= i0 + 32);
  const bool allLo = (j0 + 128 <= i0);
  for (int c0 = 0; c0 < D; c0 += 32) {
    {
      int li = tid >> 3, lc0 = (tid & 7) * 4;
      const bf16* p0 = left + (((size_t)(0 * H + h) * B + b) * N + (i0 + li)) * D + c0 + lc0;
      const bf16* p1 = left + (((size_t)(1 * H + h) * B + b) * N + (i0 + li)) * D + c0 + lc0;
      #pragma unroll
      for (int q = 0; q < 4; q++) { L0[li][lc0 + q] = b2f(p0[q]); L1[li][lc0 + q] = b2f(p1[q]); }
    }
    {
      int lj = tid >> 1, lc0 = (tid & 1) * 16;
      const float* p = qz + ((size_t)b * N + (j0 + lj)) * D + c0 + lc0;
      #pragma unroll
      for (int q = 0; q < 16; q++) QT[lc0 + q][lj] = p[q];
    }
    __syncthreads();
    if (allUp) {
      for (int c = 0; c < 32; c++) {
        float4 qv = *(const float4*)&QT[c][jg * 4];
        #pragma unroll
        for (int y = 0; y < 4; y++) {
          float l = L0[ig * 4 + y][c];
          acc[y][0] += l * qv.x; acc[y][1] += l * qv.y; acc[y][2] += l * qv.z; acc[y][3] += l * qv.w;
        }
      }
    } else if (allLo) {
      for (int c = 0; c < 32; c++) {
        float4 qv = *(const float4*)&QT[c][jg * 4];
        #pragma unroll
        for (int y = 0; y < 4; y++) {
          float l = L1[ig * 4 + y][c];
          acc[y][0] += l * qv.x; acc[y][1] += l * qv.y; acc[y][2] += l * qv.z; acc[y][3] += l * qv.w;
        }
      }
    } else {
      for (int c = 0; c < 32; c++) {
        float4 qv = *(const float4*)&QT[c][jg * 4];
        float qa[4] = {qv.x, qv.y, qv.z, qv.w};
        #pragma unroll
        for (int y = 0; y < 4; y++) {
          int ii = i0 + ig * 4 + y;
          float l0 = L0[ig * 4 + y][c], l1 = L1[ig * 4 + y][c];
          #pragma unroll
          for (int x = 0; x < 4; x++) {
            int jj = j0 + jg * 4 + x;
            float l = (jj > ii) ? l0 : ((jj < ii) ? l1 : 0.0f);
            acc[y][x] += l * qa[x];
          }
        }
      }
    }
    __syncthreads();
  }
  const int* mb = mask + b * N;
  #pragma unroll
  for (int y = 0; y < 4; y++) {
    int ii = i0 + ig * 4 + y;
    int miv = mb[ii];
    float* dst = S + (((size_t)b * H + h) * N + ii) * SW + j0 + jg * 4;
    #pragma unroll
    for (int x = 0; x < 4; x++) {
      int jj = j0 + jg * 4 + x;
      float v = (jj == ii) ? 0.0f : acc[y][x];
      float bias = (miv && mb[jj]) ? 0.0f : FNEG;
      dst[x] = v + bias;
    }
  }
}

// ---------------- Gs part of S: S[b,h,i,256+g] = qz[b,i,:] . glb[g,:,h] ------
__global__ __launch_bounds__(256) void k_Gs(const float* __restrict__ qz,
                                            const float* __restrict__ glb,
                                            float* __restrict__ S) {
  const int b = blockIdx.z, h = blockIdx.y, i0 = blockIdx.x * 32;
  __shared__ float qzT[32][33];   // [i][a-chunk]
  __shared__ float Gt[32][68];    // [a-chunk][g]
  const int tid = threadIdx.x;
  const int gg = tid & 15, ig = tid >> 4;  // g = gg*4+x, i = i0+ig*2+y
  float acc[2][4] = {};
  for (int a0 = 0; a0 < D; a0 += 32) {
    {
      int li = tid >> 3, la = (tid & 7) * 4;
      float4 v = *(const float4*)(qz + ((size_t)b * N + i0 + li) * D + a0 + la);
      qzT[li][la] = v.x; qzT[li][la + 1] = v.y; qzT[li][la + 2] = v.z; qzT[li][la + 3] = v.w;
    }
    {
      int la = tid >> 3, lg0 = (tid & 7) * 8;
      #pragma unroll
      for (int q = 0; q < 8; q++)
        Gt[la][lg0 + q] = glb[((size_t)(lg0 + q) * D + a0 + la) * H + h];
    }
    __syncthreads();
    for (int a = 0; a < 32; a++) {
      float4 gv = *(const float4*)&Gt[a][gg * 4];
      float q0 = qzT[ig * 2][a], q1 = qzT[ig * 2 + 1][a];
      acc[0][0] += q0 * gv.x; acc[0][1] += q0 * gv.y; acc[0][2] += q0 * gv.z; acc[0][3] += q0 * gv.w;
      acc[1][0] += q1 * gv.x; acc[1][1] += q1 * gv.y; acc[1][2] += q1 * gv.z; acc[1][3] += q1 * gv.w;
    }
    __syncthreads();
  }
  #pragma unroll
  for (int y = 0; y < 2; y++) {
    int ii = i0 + ig * 2 + y;
    float* dst = S + (((size_t)b * H + h) * N + ii) * SW + N + gg * 4;
    #pragma unroll
    for (int x = 0; x < 4; x++) dst[x] = acc[y][x];
  }
}

// ---------------- softmax over SW=320 ----------------------------------------
__global__ __launch_bounds__(64) void k_softmax_S(float* __restrict__ S) {
  float* p = S + (size_t)blockIdx.x * SW;
  const int lane = threadIdx.x;
  float v[5];
  #pragma unroll
  for (int e = 0; e < 5; e++) v[e] = p[lane + e * 64];
  float m = v[0];
  #pragma unroll
  for (int e = 1; e < 5; e++) m = fmaxf(m, v[e]);
  #pragma unroll
  for (int off = 32; off; off >>= 1) m = fmaxf(m, __shfl_xor(m, off));
  float s = 0.f;
  #pragma unroll
  for (int e = 0; e < 5; e++) { v[e] = __expf(v[e] - m); s += v[e]; }
  #pragma unroll
  for (int off = 32; off; off >>= 1) s += __shfl_xor(s, off);
  float inv = 1.0f / s;
  #pragma unroll
  for (int e = 0; e < 5; e++) p[lane + e * 64] = v[e] * inv;
}

// ---------------- M1[b,i,a] += sum_h,j qh[b,h,i,j]*rightSel[j,a] -------------
__global__ __launch_bounds__(256) void k_M1(const float* __restrict__ S,
                                            const bf16* __restrict__ right,
                                            float* __restrict__ out) {
  const int b = blockIdx.z, h = blockIdx.y, i0 = blockIdx.x * 32;
  __shared__ float qhT[32][33];               // [i][j-chunk]
  __shared__ float R0[32][132], R1[32][132];  // [j][a]
  const int tid = threadIdx.x;
  const int ag = tid & 31, ig = tid >> 5;     // a = ag*4+x, i = i0+ig*4+y
  float acc[4][4] = {};
  for (int j0 = 0; j0 < N; j0 += 32) {
    {
      int li = tid >> 3, lj0 = (tid & 7) * 4;
      const float* p = S + (((size_t)b * H + h) * N + i0 + li) * SW + j0 + lj0;
      #pragma unroll
      for (int q = 0; q < 4; q++) qhT[li][lj0 + q] = p[q];
    }
    {
      int lj = tid >> 3, la0 = (tid & 7) * 16;
      const bf16* p0 = right + (((size_t)(0 * H + h) * B + b) * N + j0 + lj) * D + la0;
      const bf16* p1 = right + (((size_t)(1 * H + h) * B + b) * N + j0 + lj) * D + la0;
      #pragma unroll
      for (int q = 0; q < 16; q++) { R0[lj][la0 + q] = b2f(p0[q]); R1[lj][la0 + q] = b2f(p1[q]); }
    }
    __syncthreads();
    if (j0 > i0) {
      for (int j = 0; j < 32; j++) {
        float4 rv = *(const float4*)&R0[j][ag * 4];
        #pragma unroll
        for (int y = 0; y < 4; y++) {
          float q = qhT[ig * 4 + y][j];
          acc[y][0] += q * rv.x; acc[y][1] += q * rv.y; acc[y][2] += q * rv.z; acc[y][3] += q * rv.w;
        }
      }
    } else if (j0 < i0) {
      for (int j = 0; j < 32; j++) {
        float4 rv = *(const float4*)&R1[j][ag * 4];
        #pragma unroll
        for (int y = 0; y < 4; y++) {
          float q = qhT[ig * 4 + y][j];
          acc[y][0] += q * rv.x; acc[y][1] += q * rv.y; acc[y][2] += q * rv.z; acc[y][3] += q * rv.w;
        }
      }
    } else {
      for (int j = 0; j < 32; j++) {
        float4 r0 = *(const float4*)&R0[j][ag * 4];
        float4 r1 = *(const float4*)&R1[j][ag * 4];
        #pragma unroll
        for (int y = 0; y < 4; y++) {
          int ii = ig * 4 + y;
          float q = qhT[ii][j];
          float rx, ry, rz, rw;
          if (j > ii)      { rx = r0.x; ry = r0.y; rz = r0.z; rw = r0.w; }
          else if (j < ii) { rx = r1.x; ry = r1.y; rz = r1.z; rw = r1.w; }
          else             { rx = 0.f; ry = 0.f; rz = 0.f; rw = 0.f; }
          acc[y][0] += q * rx; acc[y][1] += q * ry; acc[y][2] += q * rz; acc[y][3] += q * rw;
        }
      }
    }
    __syncthreads();
  }
  #pragma unroll
  for (int y = 0; y < 4; y++) {
    int ii = i0 + ig * 4 + y;
    float* dst = out + ((size_t)b * N + ii) * D + ag * 4;
    #pragma unroll
    for (int x = 0; x < 4; x++) atomicAdd(&dst[x], acc[y][x]);
  }
}

// ---------------- M2[b,j,c] += sum_h,i qh[b,h,i,j]*leftSel[i,c] --------------
__global__ __launch_bounds__(256) void k_M2(const float* __restrict__ S,
                                            const bf16* __restrict__ left,
                                            float* __restrict__ out) {
  const int b = blockIdx.z, h = blockIdx.y, j0 = blockIdx.x * 32;
  __shared__ float qhT[32][33];               // [i-chunk][j]
  __shared__ float L0[32][132], L1[32][132];  // [i][c]
  const int tid = threadIdx.x;
  const int cg = tid & 31, jg = tid >> 5;     // c = cg*4+x, j = j0+jg*4+y
  float acc[4][4] = {};
  for (int i0 = 0; i0 < N; i0 += 32) {
    {
      int li = tid >> 3, lj0 = (tid & 7) * 4;
      const float* p = S + (((size_t)b * H + h) * N + i0 + li) * SW + j0 + lj0;
      #pragma unroll
      for (int q = 0; q < 4; q++) qhT[li][lj0 + q] = p[q];
    }
    {
      int li = tid >> 3, lc0 = (tid & 7) * 16;
      const bf16* p0 = left + (((size_t)(0 * H + h) * B + b) * N + i0 + li) * D + lc0;
      const bf16* p1 = left + (((size_t)(1 * H + h) * B + b) * N + i0 + li) * D + lc0;
      #pragma unroll
      for (int q = 0; q < 16; q++) { L0[li][lc0 + q] = b2f(p0[q]); L1[li][lc0 + q] = b2f(p1[q]); }
    }
    __syncthreads();
    if (i0 < j0) {
      for (int i = 0; i < 32; i++) {
        float4 lv = *(const float4*)&L0[i][cg * 4];
        #pragma unroll
        for (int y = 0; y < 4; y++) {
          float q = qhT[i][jg * 4 + y];
          acc[y][0] += q * lv.x; acc[y][1] += q * lv.y; acc[y][2] += q * lv.z; acc[y][3] += q * lv.w;
        }
      }
    } else if (i0 > j0) {
      for (int i = 0; i < 32; i++) {
        float4 lv = *(const float4*)&L1[i][cg * 4];
        #pragma unroll
        for (int y = 0; y < 4; y++) {
          float q = qhT[i][jg * 4 + y];
          acc[y][0] += q * lv.x; acc[y][1] += q * lv.y; acc[y][2] += q * lv.z; acc[y][3] += q * lv.w;
        }
      }
    } else {
      for (int i = 0; i < 32; i++) {
        float4 l0 = *(const float4*)&L0[i][cg * 4];
        float4 l1 = *(const float4*)&L1[i][cg * 4];
        #pragma unroll
        for (int y = 0; y < 4; y++) {
          int jj = jg * 4 + y;
          float q = qhT[i][jj];
          float lx, ly, lz, lw;
          if (i < jj)      { lx = l0.x; ly = l0.y; lz = l0.z; lw = l0.w; }
          else if (i > jj) { lx = l1.x; ly = l1.y; lz = l1.z; lw = l1.w; }
          else             { lx = 0.f; ly = 0.f; lz = 0.f; lw = 0.f; }
          acc[y][0] += q * lx; acc[y][1] += q * ly; acc[y][2] += q * lz; acc[y][3] += q * lw;
        }
      }
    }
    __syncthreads();
  }
  #pragma unroll
  for (int y = 0; y < 4; y++) {
    int jj = j0 + jg * 4 + y;
    float* dst = out + ((size_t)b * N + jj) * D + cg * 4;
    #pragma unroll
    for (int x = 0; x < 4; x++) atomicAdd(&dst[x], acc[y][x]);
  }
}

// ---------------- MG[b,i,a] += sum_g qh_glb[b,h,i,g]*glb[g,a,h] --------------
__global__ __launch_bounds__(256) void k_MG(const float* __restrict__ S,
                                            const float* __restrict__ glb,
                                            float* __restrict__ out) {
  const int b = blockIdx.z, h = blockIdx.y, i0 = blockIdx.x * 32;
  __shared__ float qhG[32][68];   // [i][g]
  __shared__ float Gt[64][132];   // [g][a]
  const int tid = threadIdx.x;
  const int ag = tid & 31, ig = tid >> 5;  // a = ag*4+x, i = i0+ig*4+y
  float acc[4][4] = {};
  {
    int li = tid >> 3, lg0 = (tid & 7) * 8;
    const float* p = S + (((size_t)b * H + h) * N + i0 + li) * SW + N + lg0;
    #pragma unroll
    for (int q = 0; q < 8; q++) qhG[li][lg0 + q] = p[q];
  }
  {
    int lg = tid >> 2, la0 = (tid & 3) * 32;
    #pragma unroll
    for (int q = 0; q < 32; q++) Gt[lg][la0 + q] = glb[((size_t)lg * D + la0 + q) * H + h];
  }
  __syncthreads();
  for (int g = 0; g < 64; g++) {
    float4 gv = *(const float4*)&Gt[g][ag * 4];
    #pragma unroll
    for (int y = 0; y < 4; y++) {
      float q = qhG[ig * 4 + y][g];
      acc[y][0] += q * gv.x; acc[y][1] += q * gv.y; acc[y][2] += q * gv.z; acc[y][3] += q * gv.w;
    }
  }
  #pragma unroll
  for (int y = 0; y < 4; y++) {
    int ii = i0 + ig * 4 + y;
    float* dst = out + ((size_t)b * N + ii) * D + ag * 4;
    #pragma unroll
    for (int x = 0; x < 4; x++) atomicAdd(&dst[x], acc[y][x]);
  }
}

// -----------------------------------------------------------------------------
extern "C" void kernel_launch(void* const* d_in, const int* in_sizes, int n_in,
                              void* d_out, int out_size, void* d_ws, size_t ws_size,
                              hipStream_t stream) {
  (void)in_sizes; (void)n_in; (void)out_size; (void)ws_size;
  const float* x    = (const float*)d_in[0];
  const int*   mask = (const int*)d_in[1];
  const float* tern = (const float*)d_in[2];
  const float* glb  = (const float*)d_in[3];
  float* out = (float*)d_out;

  // workspace carve-up (≈106 MB)
  float* qz   = (float*)d_ws;                          // B*N*D f32
  bf16*  left = (bf16*)(qz + (size_t)B * N * D);       // 2*H*B*N*D bf16
  bf16*  right = left + (size_t)2 * H * B * N * D;     // 2*H*B*N*D bf16
  float* S    = (float*)(right + (size_t)2 * H * B * N * D);  // B*H*N*SW f32

  for (int it = 0; it < NITER; ++it) {
    const float* Qsrc = (it == 0) ? x : out;
    k_softmax_qz<<<B * N, 64, 0, stream>>>(Qsrc, qz);
    k_init<<<(B * N * D / 4) / 256, 256, 0, stream>>>(x, out);
    k_proj<false><<<dim3(B * N / 32, 16), 256, 0, stream>>>(qz, tern, left);
    k_proj<true ><<<dim3(B * N / 32, 16), 256, 0, stream>>>(qz, tern, right);
    k_F <<<dim3(16, H, B), 256, 0, stream>>>(qz, left, mask, S);
    k_Gs<<<dim3(N / 32, H, B), 256, 0, stream>>>(qz, glb, S);
    k_softmax_S<<<B * H * N, 64, 0, stream>>>(S);
    k_M1<<<dim3(N / 32, H, B), 256, 0, stream>>>(S, right, out);
    k_M2<<<dim3(N / 32, H, B), 256, 0, stream>>>(S, left, out);
    k_MG<<<dim3(N / 32, H, B), 256, 0, stream>>>(S, glb, out);
  }
}

// Round 2
// 683.765 us; speedup vs baseline: 3.2344x; 3.2344x over previous
//
#include <hip/hip_runtime.h>
#include <hip/hip_bf16.h>

using bf16 = __hip_bfloat16;
typedef __bf16 bf16x8 __attribute__((ext_vector_type(8)));
typedef float f32x4 __attribute__((ext_vector_type(4)));
typedef unsigned short u16x8 __attribute__((ext_vector_type(8)));
typedef unsigned short u16x4 __attribute__((ext_vector_type(4)));

constexpr int B_ = 16, N_ = 256, H_ = 8;
constexpr int BN = 4096;            // B_*N_
constexpr int SW = 320;             // N_+G_
constexpr float FNEG = -1000000000.0f;

__device__ __forceinline__ float b2f(bf16 v){ return __bfloat162float(v); }
__device__ __forceinline__ bf16 f2b(float v){ return __float2bfloat16(v); }
__device__ __forceinline__ bf16x8 ldf(const bf16* p){ return *(const bf16x8*)p; }
__device__ __forceinline__ f32x4 mfma16(bf16x8 a, bf16x8 b, f32x4 c){
  return __builtin_amdgcn_mfma_f32_16x16x32_bf16(a, b, c, 0, 0, 0);
}

// ---- one-time: permute ternary/global_ into bf16 B^T layouts ----------------
__global__ __launch_bounds__(256) void k_prep(const float* __restrict__ tern,
                                              const float* __restrict__ glb,
                                              bf16* __restrict__ TL, bf16* __restrict__ TR,
                                              bf16* __restrict__ GB, bf16* __restrict__ GT){
  int t = blockIdx.x*256 + threadIdx.x;        // 0..262143
  {
    int kh = t>>14, rest = t&16383;
    int k = kh>>3, h = kh&7;
    int r = rest>>7, cc = rest&127;
    // TL[kh][c=r][a=cc] = tern[k][a=cc][c=r][h]
    TL[t] = f2b(tern[(((size_t)k*128 + cc)*128 + r)*8 + h]);
    // TR[kh][a=r][c=cc] = tern[k][a=r][c=cc][h]
    TR[t] = f2b(tern[(((size_t)k*128 + r)*128 + cc)*8 + h]);
  }
  if (t < 65536){
    int h = t>>13, rest = t&8191;
    { int g = rest>>7, a = rest&127;   // GB[h][g][a] = glb[g][a][h]
      GB[t] = f2b(glb[((size_t)g*128 + a)*8 + h]); }
    { int a = rest>>6, g = rest&63;    // GT[h][a][g] = glb[g][a][h]
      GT[t] = f2b(glb[((size_t)g*128 + a)*8 + h]); }
  }
}

// ---- qz = softmax(Q, -1) rows of 128, bf16 out ------------------------------
__global__ __launch_bounds__(256) void k_softmax_qz(const float* __restrict__ Q,
                                                    bf16* __restrict__ qzb){
  int row = blockIdx.x*4 + (threadIdx.x>>6);
  int lane = threadIdx.x&63;
  const float* q = Q + (size_t)row*128;
  float v0 = q[lane], v1 = q[lane+64];
  float m = fmaxf(v0, v1);
  #pragma unroll
  for (int o=32;o;o>>=1) m = fmaxf(m, __shfl_xor(m, o));
  float e0 = __expf(v0-m), e1 = __expf(v1-m), s = e0+e1;
  #pragma unroll
  for (int o=32;o;o>>=1) s += __shfl_xor(s, o);
  float inv = 1.f/s;
  bf16* o_ = qzb + (size_t)row*128;
  o_[lane] = f2b(e0*inv); o_[lane+64] = f2b(e1*inv);
}

// ---- proj: left[kh][r][c] (+leftT) or rightT[kh][a][r] ----------------------
template<bool RIGHT>
__global__ __launch_bounds__(256) void k_proj(const bf16* __restrict__ qzb,
                                              const bf16* __restrict__ Tm,
                                              bf16* __restrict__ outN,
                                              bf16* __restrict__ outT){
  const int kh = blockIdx.z;
  const int wi = threadIdx.x>>7, wj = (threadIdx.x>>6)&1;
  const int lane = threadIdx.x&63, lr = lane&15, kg = lane>>4;
  const int r0 = blockIdx.x*64 + wi*32;
  const int c0 = blockIdx.y*64 + wj*32;
  const bf16* A  = qzb + (size_t)r0*128;
  const bf16* Bb = Tm + ((size_t)kh*128 + c0)*128;
  f32x4 acc[2][2] = {};
  for (int k0=0;k0<128;k0+=32){
    bf16x8 a0 = ldf(A  + (size_t)lr*128      + k0 + kg*8);
    bf16x8 a1 = ldf(A  + (size_t)(lr+16)*128 + k0 + kg*8);
    bf16x8 b0 = ldf(Bb + (size_t)lr*128      + k0 + kg*8);
    bf16x8 b1 = ldf(Bb + (size_t)(lr+16)*128 + k0 + kg*8);
    acc[0][0]=mfma16(a0,b0,acc[0][0]); acc[0][1]=mfma16(a0,b1,acc[0][1]);
    acc[1][0]=mfma16(a1,b0,acc[1][0]); acc[1][1]=mfma16(a1,b1,acc[1][1]);
  }
  #pragma unroll
  for (int fi=0;fi<2;fi++){
    int rb = r0 + fi*16 + kg*4;
    #pragma unroll
    for (int fj=0;fj<2;fj++){
      int col = c0 + fj*16 + lr;
      u16x4 pk;
      #pragma unroll
      for (int r=0;r<4;r++) pk[r] = __builtin_bit_cast(unsigned short, f2b(acc[fi][fj][r]));
      *(u16x4*)(outT + ((size_t)kh*128 + col)*BN + rb) = pk;
      if constexpr (!RIGHT){
        #pragma unroll
        for (int r=0;r<4;r++)
          outN[((size_t)kh*BN + rb + r)*128 + col] = f2b(acc[fi][fj][r]);
      }
    }
  }
}

// ---- S = [F(+bias) | Gs] in bf16 --------------------------------------------
__global__ __launch_bounds__(256) void k_FS(const bf16* __restrict__ qzb,
                                            const bf16* __restrict__ left,
                                            const bf16* __restrict__ GB,
                                            const int* __restrict__ mask,
                                            bf16* __restrict__ S){
  const int bh = blockIdx.z, b = bh>>3, h = bh&7;
  const int wi = threadIdx.x>>7, wj = (threadIdx.x>>6)&1;
  const int lane = threadIdx.x&63, lr = lane&15, kg = lane>>4;
  const int i0 = blockIdx.x*64 + wi*32;
  const bf16* qzB = qzb + (size_t)b*256*128;
  f32x4 acc[2][2] = {};
  if (blockIdx.y == 4){            // Gs columns
    const bf16* A  = qzB + (size_t)i0*128;
    const bf16* Bb = GB + ((size_t)h*64 + wj*32)*128;
    for (int k0=0;k0<128;k0+=32){
      bf16x8 a0=ldf(A +(size_t)lr*128     +k0+kg*8), a1=ldf(A +(size_t)(lr+16)*128+k0+kg*8);
      bf16x8 b0=ldf(Bb+(size_t)lr*128     +k0+kg*8), b1=ldf(Bb+(size_t)(lr+16)*128+k0+kg*8);
      acc[0][0]=mfma16(a0,b0,acc[0][0]); acc[0][1]=mfma16(a0,b1,acc[0][1]);
      acc[1][0]=mfma16(a1,b0,acc[1][0]); acc[1][1]=mfma16(a1,b1,acc[1][1]);
    }
    #pragma unroll
    for (int fi=0;fi<2;fi++)
      #pragma unroll
      for (int fj=0;fj<2;fj++)
        #pragma unroll
        for (int r=0;r<4;r++){
          int i = i0 + fi*16 + kg*4 + r, g = wj*32 + fj*16 + lr;
          S[((size_t)bh*256 + i)*SW + 256 + g] = f2b(acc[fi][fj][r]);
        }
    return;
  }
  const int j0 = blockIdx.y*64 + wj*32;
  const bool dual = (blockIdx.x == blockIdx.y);
  const bf16* Q  = qzB + (size_t)j0*128;
  const bf16* L0 = left + ((size_t)h*BN     + b*256 + i0)*128;
  const bf16* L1 = left + ((size_t)(8+h)*BN + b*256 + i0)*128;
  const bf16* Ls = (blockIdx.y > blockIdx.x) ? L0 : L1;
  f32x4 acc1[2][2] = {};
  for (int k0=0;k0<128;k0+=32){
    bf16x8 b0=ldf(Q+(size_t)lr*128+k0+kg*8), b1=ldf(Q+(size_t)(lr+16)*128+k0+kg*8);
    if (!dual){
      bf16x8 a0=ldf(Ls+(size_t)lr*128+k0+kg*8), a1=ldf(Ls+(size_t)(lr+16)*128+k0+kg*8);
      acc[0][0]=mfma16(a0,b0,acc[0][0]); acc[0][1]=mfma16(a0,b1,acc[0][1]);
      acc[1][0]=mfma16(a1,b0,acc[1][0]); acc[1][1]=mfma16(a1,b1,acc[1][1]);
    } else {
      bf16x8 a0=ldf(L0+(size_t)lr*128+k0+kg*8), a1=ldf(L0+(size_t)(lr+16)*128+k0+kg*8);
      acc[0][0]=mfma16(a0,b0,acc[0][0]); acc[0][1]=mfma16(a0,b1,acc[0][1]);
      acc[1][0]=mfma16(a1,b0,acc[1][0]); acc[1][1]=mfma16(a1,b1,acc[1][1]);
      bf16x8 c0=ldf(L1+(size_t)lr*128+k0+kg*8), c1=ldf(L1+(size_t)(lr+16)*128+k0+kg*8);
      acc1[0][0]=mfma16(c0,b0,acc1[0][0]); acc1[0][1]=mfma16(c0,b1,acc1[0][1]);
      acc1[1][0]=mfma16(c1,b0,acc1[1][0]); acc1[1][1]=mfma16(c1,b1,acc1[1][1]);
    }
  }
  const int* mb = mask + b*256;
  #pragma unroll
  for (int fi=0;fi<2;fi++){
    #pragma unroll
    for (int r=0;r<4;r++){
      int i = i0 + fi*16 + kg*4 + r;
      int mi = mb[i];
      #pragma unroll
      for (int fj=0;fj<2;fj++){
        int j = j0 + fj*16 + lr;
        float v = acc[fi][fj][r];
        if (dual) v = (j>i) ? acc[fi][fj][r] : ((j<i) ? acc1[fi][fj][r] : 0.f);
        float bias = (mi && mb[j]) ? 0.f : FNEG;
        S[((size_t)bh*256 + i)*SW + j] = f2b(v + bias);
      }
    }
  }
}

// ---- softmax over 320, bf16 in/out ------------------------------------------
__global__ __launch_bounds__(256) void k_softmax_S(const bf16* __restrict__ S,
                                                   bf16* __restrict__ qh){
  int row = blockIdx.x*4 + (threadIdx.x>>6);
  int lane = threadIdx.x&63;
  const bf16* p = S + (size_t)row*SW;
  float v[5];
  #pragma unroll
  for (int e=0;e<5;e++) v[e] = b2f(p[lane + e*64]);
  float m = v[0];
  #pragma unroll
  for (int e=1;e<5;e++) m = fmaxf(m, v[e]);
  #pragma unroll
  for (int o=32;o;o>>=1) m = fmaxf(m, __shfl_xor(m, o));
  float s = 0.f;
  #pragma unroll
  for (int e=0;e<5;e++){ v[e] = __expf(v[e]-m); s += v[e]; }
  #pragma unroll
  for (int o=32;o;o>>=1) s += __shfl_xor(s, o);
  float inv = 1.f/s;
  bf16* o_ = qh + (size_t)row*SW;
  #pragma unroll
  for (int e=0;e<5;e++) o_[lane + e*64] = f2b(v[e]*inv);
}

// ---- transpose qh loc part: qhT[bh][j][i] -----------------------------------
__global__ __launch_bounds__(256) void k_qhT(const bf16* __restrict__ qh,
                                             bf16* __restrict__ qhT){
  const int bh = blockIdx.y;
  const int i0 = (blockIdx.x&3)*64, j0 = (blockIdx.x>>2)*64;
  __shared__ unsigned short t[64][72];
  const int r = threadIdx.x>>2, cs = (threadIdx.x&3)*16;
  const unsigned short* src = (const unsigned short*)qh + ((size_t)bh*256 + i0 + r)*SW + j0 + cs;
  #pragma unroll
  for (int e=0;e<16;e++) t[r][cs+e] = src[e];
  __syncthreads();
  unsigned short* dst = (unsigned short*)qhT + ((size_t)bh*256 + j0 + r)*256 + i0 + cs;
  u16x8 p0, p1;
  #pragma unroll
  for (int e=0;e<8;e++) p0[e] = t[cs+e][r];
  #pragma unroll
  for (int e=0;e<8;e++) p1[e] = t[cs+8+e][r];
  *(u16x8*)dst = p0; *(u16x8*)(dst+8) = p1;
}

// ---- M kernels: rows from qh-rows (A), triangle-selected B, per-h partials --
// GT-pass (contraction k > row r) uses Bgt; LT-pass uses Blt.
template<int AS, bool GLB, bool ACC>
__global__ __launch_bounds__(256) void k_M(const bf16* __restrict__ qh,
                                           const bf16* __restrict__ Bgt,
                                           const bf16* __restrict__ Blt,
                                           const bf16* __restrict__ Bglb,
                                           float* __restrict__ Mp){
  const int bh = blockIdx.z, b = bh>>3, h = bh&7;
  const int wi = threadIdx.x>>7, wj = (threadIdx.x>>6)&1;
  const int lane = threadIdx.x&63, lr = lane&15, kg = lane>>4;
  const int r0 = blockIdx.x*64 + wi*32;
  const int c0 = blockIdx.y*64 + wj*32;
  const bf16* A  = qh + ((size_t)bh*256 + r0)*AS;
  const bf16* Bg = Bgt + (size_t)h*128*BN + b*256;
  const bf16* Bl = Blt + (size_t)h*128*BN + b*256;
  f32x4 acc[2][2] = {};
  for (int kt=0;kt<8;kt++){
    const int k0 = kt*32;
    bf16x8 bg0 = ldf(Bg + (size_t)(c0+lr)*BN    + k0 + kg*8);
    bf16x8 bg1 = ldf(Bg + (size_t)(c0+16+lr)*BN + k0 + kg*8);
    bf16x8 bl0 = ldf(Bl + (size_t)(c0+lr)*BN    + k0 + kg*8);
    bf16x8 bl1 = ldf(Bl + (size_t)(c0+16+lr)*BN + k0 + kg*8);
    #pragma unroll
    for (int fi=0;fi<2;fi++){
      const int ib = r0 + fi*16;
      bf16x8 a = ldf(A + (size_t)(fi*16+lr)*AS + k0 + kg*8);
      if (k0 >= ib + 16){
        acc[fi][0]=mfma16(a,bg0,acc[fi][0]); acc[fi][1]=mfma16(a,bg1,acc[fi][1]);
      } else if (k0 + 32 <= ib){
        acc[fi][0]=mfma16(a,bl0,acc[fi][0]); acc[fi][1]=mfma16(a,bl1,acc[fi][1]);
      } else {
        u16x8 u = __builtin_bit_cast(u16x8, a), ug, ul;
        const int tt = k0 + kg*8 - ib - lr;   // (k - r) for element e is tt+e
        #pragma unroll
        for (int e=0;e<8;e++){
          ug[e] = (tt+e>0) ? u[e] : (unsigned short)0;
          ul[e] = (tt+e<0) ? u[e] : (unsigned short)0;
        }
        bf16x8 ag = __builtin_bit_cast(bf16x8, ug), al = __builtin_bit_cast(bf16x8, ul);
        acc[fi][0]=mfma16(ag,bg0,acc[fi][0]); acc[fi][1]=mfma16(ag,bg1,acc[fi][1]);
        acc[fi][0]=mfma16(al,bl0,acc[fi][0]); acc[fi][1]=mfma16(al,bl1,acc[fi][1]);
      }
    }
  }
  if constexpr (GLB){
    const bf16* Bgl = Bglb + (size_t)h*128*64;
    #pragma unroll
    for (int kt=0;kt<2;kt++){
      const int k0 = kt*32;
      bf16x8 b0 = ldf(Bgl + (size_t)(c0+lr)*64    + k0 + kg*8);
      bf16x8 b1 = ldf(Bgl + (size_t)(c0+16+lr)*64 + k0 + kg*8);
      #pragma unroll
      for (int fi=0;fi<2;fi++){
        bf16x8 a = ldf(A + (size_t)(fi*16+lr)*AS + 256 + k0 + kg*8);
        acc[fi][0]=mfma16(a,b0,acc[fi][0]); acc[fi][1]=mfma16(a,b1,acc[fi][1]);
      }
    }
  }
  #pragma unroll
  for (int fi=0;fi<2;fi++)
    #pragma unroll
    for (int fj=0;fj<2;fj++)
      #pragma unroll
      for (int r=0;r<4;r++){
        int row = r0 + fi*16 + kg*4 + r;
        int col = c0 + fj*16 + lr;
        float* d = Mp + ((size_t)h*BN + b*256 + row)*128 + col;
        if constexpr (ACC) *d += acc[fi][fj][r]; else *d = acc[fi][fj][r];
      }
}

// ---- out = x + sum_h Mp[h] --------------------------------------------------
__global__ __launch_bounds__(256) void k_reduce(const float* __restrict__ x,
                                                const float* __restrict__ Mp,
                                                float* __restrict__ out){
  const size_t i = (size_t)blockIdx.x*256 + threadIdx.x;   // float4 index
  float4 v = ((const float4*)x)[i];
  #pragma unroll
  for (int h=0;h<8;h++){
    float4 m = ((const float4*)Mp)[(size_t)h*131072 + i];
    v.x+=m.x; v.y+=m.y; v.z+=m.z; v.w+=m.w;
  }
  ((float4*)out)[i] = v;
}

// -----------------------------------------------------------------------------
extern "C" void kernel_launch(void* const* d_in, const int* in_sizes, int n_in,
                              void* d_out, int out_size, void* d_ws, size_t ws_size,
                              hipStream_t stream) {
  (void)in_sizes; (void)n_in; (void)out_size; (void)ws_size;
  const float* x    = (const float*)d_in[0];
  const int*   mask = (const int*)d_in[1];
  const float* tern = (const float*)d_in[2];
  const float* glb  = (const float*)d_in[3];
  float* out = (float*)d_out;

  char* w = (char*)d_ws;
  auto alloc = [&](size_t bytes){ void* p = (void*)w; w += (bytes + 255) & ~(size_t)255; return p; };
  bf16* qzb    = (bf16*) alloc((size_t)BN*128*2);          // 1 MB
  bf16* left   = (bf16*) alloc((size_t)16*BN*128*2);       // 16 MB
  bf16* leftT  = (bf16*) alloc((size_t)16*BN*128*2);       // 16 MB
  bf16* rightT = (bf16*) alloc((size_t)16*BN*128*2);       // 16 MB
  bf16* S      = (bf16*) alloc((size_t)B_*H_*256*SW*2);    // 21 MB
  bf16* qh     = (bf16*) alloc((size_t)B_*H_*256*SW*2);    // 21 MB
  bf16* qhT    = (bf16*) alloc((size_t)B_*H_*256*256*2);   // 16.8 MB
  float* Mp    = (float*)alloc((size_t)8*BN*128*4);        // 16.8 MB
  bf16* TL     = (bf16*) alloc((size_t)16*128*128*2);
  bf16* TR     = (bf16*) alloc((size_t)16*128*128*2);
  bf16* GB     = (bf16*) alloc((size_t)8*64*128*2);
  bf16* GT     = (bf16*) alloc((size_t)8*64*128*2);

  k_prep<<<1024, 256, 0, stream>>>(tern, glb, TL, TR, GB, GT);

  for (int it = 0; it < 4; ++it){
    const float* Qsrc = (it == 0) ? x : out;
    k_softmax_qz<<<1024, 256, 0, stream>>>(Qsrc, qzb);
    k_proj<false><<<dim3(64,2,16), 256, 0, stream>>>(qzb, TL, left, leftT);
    k_proj<true ><<<dim3(64,2,16), 256, 0, stream>>>(qzb, TR, nullptr, rightT);
    k_FS<<<dim3(4,5,128), 256, 0, stream>>>(qzb, left, GB, mask, S);
    k_softmax_S<<<8192, 256, 0, stream>>>(S, qh);
    k_qhT<<<dim3(16,128), 256, 0, stream>>>(qh, qhT);
    // M1 (+MG): rows i from qh (width 320); j>i -> right k=0, j<i -> right k=1
    k_M<SW, true, false><<<dim3(4,2,128), 256, 0, stream>>>(
        qh, rightT, rightT + (size_t)8*128*BN, GT, Mp);
    // M2: rows j from qhT (width 256); i>j -> left k=1, i<j -> left k=0
    k_M<256, false, true><<<dim3(4,2,128), 256, 0, stream>>>(
        qhT, leftT + (size_t)8*128*BN, leftT, GT, Mp);
    k_reduce<<<512, 256, 0, stream>>>(x, Mp, out);
  }
}

// Round 4
// 676.155 us; speedup vs baseline: 3.2708x; 1.0113x over previous
//
#include <hip/hip_runtime.h>
#include <hip/hip_bf16.h>

using bf16 = __hip_bfloat16;
typedef __bf16 bf16x8 __attribute__((ext_vector_type(8)));
typedef float f32x4 __attribute__((ext_vector_type(4)));
typedef unsigned short u16x8 __attribute__((ext_vector_type(8)));
typedef unsigned short u16x4 __attribute__((ext_vector_type(4)));

constexpr int B_ = 16, H_ = 8;
constexpr int BN = 4096;            // B_*N_
constexpr int SW = 320;             // N_+G_
constexpr float FNEG = -1000000000.0f;
constexpr size_t KOFF = (size_t)8 * 16 * 128 * 256;   // k-plane stride in RT2/LT2

__device__ __forceinline__ float b2f(bf16 v){ return __bfloat162float(v); }
__device__ __forceinline__ bf16 f2b(float v){ return __float2bfloat16(v); }
__device__ __forceinline__ bf16x8 ldf(const bf16* p){ return *(const bf16x8*)p; }
__device__ __forceinline__ f32x4 mfma16(bf16x8 a, bf16x8 b, f32x4 c){
  return __builtin_amdgcn_mfma_f32_16x16x32_bf16(a, b, c, 0, 0, 0);
}

// ---- one-time: permute ternary/global_ into bf16 B^T layouts ----------------
__global__ __launch_bounds__(256) void k_prep(const float* __restrict__ tern,
                                              const float* __restrict__ glb,
                                              bf16* __restrict__ TL, bf16* __restrict__ TR,
                                              bf16* __restrict__ GB, bf16* __restrict__ GT){
  int t = blockIdx.x*256 + threadIdx.x;        // 0..262143
  {
    int kh = t>>14, rest = t&16383;
    int k = kh>>3, h = kh&7;
    int r = rest>>7, cc = rest&127;
    TL[t] = f2b(tern[(((size_t)k*128 + cc)*128 + r)*8 + h]);   // TL[kh][c][a]
    TR[t] = f2b(tern[(((size_t)k*128 + r)*128 + cc)*8 + h]);   // TR[kh][a][c]
  }
  if (t < 65536){
    int h = t>>13, rest = t&8191;
    { int g = rest>>7, a = rest&127;   // GB[h][g][a]
      GB[t] = f2b(glb[((size_t)g*128 + a)*8 + h]); }
    { int a = rest>>6, g = rest&63;    // GT[h][a][g]
      GT[t] = f2b(glb[((size_t)g*128 + a)*8 + h]); }
  }
}

// ---- it0: qz = softmax(x, -1) ------------------------------------------------
__global__ __launch_bounds__(256) void k_softmax_qz(const float* __restrict__ Q,
                                                    bf16* __restrict__ qzb){
  int row = blockIdx.x*4 + (threadIdx.x>>6);
  int lane = threadIdx.x&63;
  const float* q = Q + (size_t)row*128;
  float v0 = q[lane], v1 = q[lane+64];
  float m = fmaxf(v0, v1);
  #pragma unroll
  for (int o=32;o;o>>=1) m = fmaxf(m, __shfl_xor(m, o));
  float e0 = __expf(v0-m), e1 = __expf(v1-m), s = e0+e1;
  #pragma unroll
  for (int o=32;o;o>>=1) s += __shfl_xor(s, o);
  float inv = 1.f/s;
  bf16* o_ = qzb + (size_t)row*128;
  o_[lane] = f2b(e0*inv); o_[lane+64] = f2b(e1*inv);
}

// ---- proj (merged L/R): left[kh][bi][c] + LT2/RT2 blocked-transposed --------
// z<16: LEFT pass (Tm=TL) -> left + LT2 ; z>=16: RIGHT pass (Tm=TR) -> RT2
// LT2/RT2 layout: [(kh)*16 + b][col(128)][K-local(256)]
__global__ __launch_bounds__(256) void k_proj(const bf16* __restrict__ qzb,
                                              const bf16* __restrict__ TL,
                                              const bf16* __restrict__ TR,
                                              bf16* __restrict__ left,
                                              bf16* __restrict__ LT2,
                                              bf16* __restrict__ RT2){
  const int z = blockIdx.z; const int kh = z & 15; const bool rightP = z >= 16;
  const int wi = threadIdx.x>>7, wj = (threadIdx.x>>6)&1;
  const int lane = threadIdx.x&63, lr = lane&15, kg = lane>>4;
  const int rb0 = blockIdx.x*64, cb = blockIdx.y*64;
  const int r0 = rb0 + wi*32, c0 = cb + wj*32;
  const bf16* A  = qzb + (size_t)r0*128;
  const bf16* Bb = (rightP ? TR : TL) + ((size_t)kh*128 + c0)*128;
  f32x4 acc[2][2] = {};
  #pragma unroll
  for (int k0=0;k0<128;k0+=32){
    bf16x8 a0 = ldf(A  + (size_t)lr*128      + k0 + kg*8);
    bf16x8 a1 = ldf(A  + (size_t)(lr+16)*128 + k0 + kg*8);
    bf16x8 b0 = ldf(Bb + (size_t)lr*128      + k0 + kg*8);
    bf16x8 b1 = ldf(Bb + (size_t)(lr+16)*128 + k0 + kg*8);
    acc[0][0]=mfma16(a0,b0,acc[0][0]); acc[0][1]=mfma16(a0,b1,acc[0][1]);
    acc[1][0]=mfma16(a1,b0,acc[1][0]); acc[1][1]=mfma16(a1,b1,acc[1][1]);
  }
  __shared__ unsigned short tl[64][68];
  #pragma unroll
  for (int fi=0;fi<2;fi++)
    #pragma unroll
    for (int fj=0;fj<2;fj++){
      u16x4 pk;
      #pragma unroll
      for (int r=0;r<4;r++) pk[r] = __builtin_bit_cast(unsigned short, f2b(acc[fi][fj][r]));
      *(u16x4*)&tl[wj*32 + fj*16 + lr][wi*32 + fi*16 + kg*4] = pk;
    }
  if (!rightP){
    #pragma unroll
    for (int fi=0;fi<2;fi++){
      int rb = r0 + fi*16 + kg*4;
      #pragma unroll
      for (int fj=0;fj<2;fj++){
        int col = c0 + fj*16 + lr;
        #pragma unroll
        for (int r=0;r<4;r++)
          left[((size_t)kh*BN + rb + r)*128 + col] = f2b(acc[fi][fj][r]);
      }
    }
  }
  __syncthreads();
  const int b = rb0 >> 8, jloc = rb0 & 255;
  const int col = threadIdx.x >> 2, seg = threadIdx.x & 3;
  bf16* O = rightP ? RT2 : LT2;
  unsigned short* dst = (unsigned short*)O +
      (((size_t)kh*16 + b)*128 + cb + col)*256 + jloc + seg*16;
  const unsigned short* src = &tl[col][seg*16];
  #pragma unroll
  for (int e=0;e<4;e++) *(u16x4*)(dst + e*4) = *(const u16x4*)(src + e*4);
}

// ---- S = [F(+bias) | Gs] in bf16 --------------------------------------------
__global__ __launch_bounds__(256) void k_FS(const bf16* __restrict__ qzb,
                                            const bf16* __restrict__ left,
                                            const bf16* __restrict__ GB,
                                            const int* __restrict__ mask,
                                            bf16* __restrict__ S){
  const int bh = blockIdx.z, b = bh>>3, h = bh&7;
  const int wi = threadIdx.x>>7, wj = (threadIdx.x>>6)&1;
  const int lane = threadIdx.x&63, lr = lane&15, kg = lane>>4;
  const int i0 = blockIdx.x*64 + wi*32;
  const bf16* qzB = qzb + (size_t)b*256*128;
  f32x4 acc[2][2] = {};
  if (blockIdx.y == 4){            // Gs columns
    const bf16* A  = qzB + (size_t)i0*128;
    const bf16* Bb = GB + ((size_t)h*64 + wj*32)*128;
    #pragma unroll
    for (int k0=0;k0<128;k0+=32){
      bf16x8 a0=ldf(A +(size_t)lr*128+k0+kg*8), a1=ldf(A +(size_t)(lr+16)*128+k0+kg*8);
      bf16x8 b0=ldf(Bb+(size_t)lr*128+k0+kg*8), b1=ldf(Bb+(size_t)(lr+16)*128+k0+kg*8);
      acc[0][0]=mfma16(a0,b0,acc[0][0]); acc[0][1]=mfma16(a0,b1,acc[0][1]);
      acc[1][0]=mfma16(a1,b0,acc[1][0]); acc[1][1]=mfma16(a1,b1,acc[1][1]);
    }
    #pragma unroll
    for (int fi=0;fi<2;fi++)
      #pragma unroll
      for (int fj=0;fj<2;fj++)
        #pragma unroll
        for (int r=0;r<4;r++){
          int i = i0 + fi*16 + kg*4 + r, g = wj*32 + fj*16 + lr;
          S[((size_t)bh*256 + i)*SW + 256 + g] = f2b(acc[fi][fj][r]);
        }
    return;
  }
  const int j0 = blockIdx.y*64 + wj*32;
  const bool dual = (blockIdx.x == blockIdx.y);
  const bf16* Q  = qzB + (size_t)j0*128;
  const bf16* L0 = left + ((size_t)h*BN     + b*256 + i0)*128;
  const bf16* L1 = left + ((size_t)(8+h)*BN + b*256 + i0)*128;
  const bf16* Ls = (blockIdx.y > blockIdx.x) ? L0 : L1;
  f32x4 acc1[2][2] = {};
  #pragma unroll
  for (int k0=0;k0<128;k0+=32){
    bf16x8 b0=ldf(Q+(size_t)lr*128+k0+kg*8), b1=ldf(Q+(size_t)(lr+16)*128+k0+kg*8);
    if (!dual){
      bf16x8 a0=ldf(Ls+(size_t)lr*128+k0+kg*8), a1=ldf(Ls+(size_t)(lr+16)*128+k0+kg*8);
      acc[0][0]=mfma16(a0,b0,acc[0][0]); acc[0][1]=mfma16(a0,b1,acc[0][1]);
      acc[1][0]=mfma16(a1,b0,acc[1][0]); acc[1][1]=mfma16(a1,b1,acc[1][1]);
    } else {
      bf16x8 a0=ldf(L0+(size_t)lr*128+k0+kg*8), a1=ldf(L0+(size_t)(lr+16)*128+k0+kg*8);
      acc[0][0]=mfma16(a0,b0,acc[0][0]); acc[0][1]=mfma16(a0,b1,acc[0][1]);
      acc[1][0]=mfma16(a1,b0,acc[1][0]); acc[1][1]=mfma16(a1,b1,acc[1][1]);
      bf16x8 c0=ldf(L1+(size_t)lr*128+k0+kg*8), c1=ldf(L1+(size_t)(lr+16)*128+k0+kg*8);
      acc1[0][0]=mfma16(c0,b0,acc1[0][0]); acc1[0][1]=mfma16(c0,b1,acc1[0][1]);
      acc1[1][0]=mfma16(c1,b0,acc1[1][0]); acc1[1][1]=mfma16(c1,b1,acc1[1][1]);
    }
  }
  const int* mb = mask + b*256;
  #pragma unroll
  for (int fi=0;fi<2;fi++){
    #pragma unroll
    for (int r=0;r<4;r++){
      int i = i0 + fi*16 + kg*4 + r;
      int mi = mb[i];
      #pragma unroll
      for (int fj=0;fj<2;fj++){
        int j = j0 + fj*16 + lr;
        float v = acc[fi][fj][r];
        if (dual) v = (j>i) ? acc[fi][fj][r] : ((j<i) ? acc1[fi][fj][r] : 0.f);
        float bias = (mi && mb[j]) ? 0.f : FNEG;
        S[((size_t)bh*256 + i)*SW + j] = f2b(v + bias);
      }
    }
  }
}

// ---- softmax over 320 + emit qh rows AND blocked transpose qhT2 -------------
// qhT2 layout: [bh][ib(4)][j(256)][i-in-64]
__global__ __launch_bounds__(256) void k_softmax_T(const bf16* __restrict__ S,
                                                   bf16* __restrict__ qh,
                                                   bf16* __restrict__ qhT2){
  const int bh = blockIdx.y, i0 = blockIdx.x*64;
  __shared__ unsigned short t2[256][68];
  const int sub = threadIdx.x>>6, lane = threadIdx.x&63;
  for (int rr=0; rr<16; rr++){
    const int r = rr*4 + sub;                 // 0..63
    const bf16* p = S + ((size_t)bh*256 + i0 + r)*SW;
    float v[5];
    #pragma unroll
    for (int e=0;e<5;e++) v[e] = b2f(p[lane + e*64]);
    float m = v[0];
    #pragma unroll
    for (int e=1;e<5;e++) m = fmaxf(m, v[e]);
    #pragma unroll
    for (int o=32;o;o>>=1) m = fmaxf(m, __shfl_xor(m, o));
    float s = 0.f;
    #pragma unroll
    for (int e=0;e<5;e++){ v[e] = __expf(v[e]-m); s += v[e]; }
    #pragma unroll
    for (int o=32;o;o>>=1) s += __shfl_xor(s, o);
    float inv = 1.f/s;
    bf16* o_ = qh + ((size_t)bh*256 + i0 + r)*SW;
    #pragma unroll
    for (int e=0;e<5;e++){
      bf16 ov = f2b(v[e]*inv);
      o_[lane + e*64] = ov;
      if (e < 4) t2[lane + e*64][r] = __builtin_bit_cast(unsigned short, ov);
    }
  }
  __syncthreads();
  const int j = threadIdx.x;
  unsigned short* dst = (unsigned short*)qhT2 + (((size_t)bh*4 + blockIdx.x)*256 + j)*64;
  #pragma unroll
  for (int e0=0;e0<64;e0+=4)
    *(u16x4*)(dst + e0) = *(const u16x4*)&t2[j][e0];
}

// ---- M kernels, 2 h per block, accumulate across h into Mp[hg] --------------
// MODE 0: M1+MG  A=qh rows i (stride 320), Bg=RT2 k0, Bl=RT2 k1, + GT,  store
// MODE 1: M2     A=qhT2 blocked rows j,    Bg=LT2 k1, Bl=LT2 k0,        +=
template<int MODE>
__global__ __launch_bounds__(256) void k_M(const bf16* __restrict__ Aall,
                                           const bf16* __restrict__ Bg_,
                                           const bf16* __restrict__ Bl_,
                                           const bf16* __restrict__ GT,
                                           float* __restrict__ Mp){
  const int z = blockIdx.z, b = z>>2, hg = z&3;
  const int wi = threadIdx.x>>7, wj = (threadIdx.x>>6)&1;
  const int lane = threadIdx.x&63, lr = lane&15, kg = lane>>4;
  const int r0 = blockIdx.x*64 + wi*32;
  const int c0 = blockIdx.y*64 + wj*32;
  f32x4 acc[2][2] = {};
  #pragma unroll
  for (int hh=0;hh<2;hh++){
    const int h = hg*2 + hh;
    const bf16* Bgh = Bg_ + (((size_t)h*16 + b)*128)*256;
    const bf16* Blh = Bl_ + (((size_t)h*16 + b)*128)*256;
    const bf16* A0 = (MODE==0) ? Aall + ((size_t)(b*8+h)*256)*SW
                               : Aall + ((size_t)(b*8+h)*4)*256*64;
    for (int kt=0;kt<8;kt++){
      const int k0 = kt*32;
      bf16x8 bg0 = ldf(Bgh + (size_t)(c0+lr)*256    + k0 + kg*8);
      bf16x8 bg1 = ldf(Bgh + (size_t)(c0+16+lr)*256 + k0 + kg*8);
      bf16x8 bl0 = ldf(Blh + (size_t)(c0+lr)*256    + k0 + kg*8);
      bf16x8 bl1 = ldf(Blh + (size_t)(c0+16+lr)*256 + k0 + kg*8);
      #pragma unroll
      for (int fi=0;fi<2;fi++){
        const int ib = r0 + fi*16;
        bf16x8 a;
        if constexpr (MODE==0)
          a = ldf(A0 + (size_t)(ib+lr)*SW + k0 + kg*8);
        else
          a = ldf(A0 + (((size_t)(k0>>6))*256 + ib + lr)*64 + (k0&63) + kg*8);
        if (k0 >= ib + 16){
          acc[fi][0]=mfma16(a,bg0,acc[fi][0]); acc[fi][1]=mfma16(a,bg1,acc[fi][1]);
        } else if (k0 + 32 <= ib){
          acc[fi][0]=mfma16(a,bl0,acc[fi][0]); acc[fi][1]=mfma16(a,bl1,acc[fi][1]);
        } else {
          u16x8 u = __builtin_bit_cast(u16x8, a), ug, ul;
          const int tt = k0 + kg*8 - ib - lr;
          #pragma unroll
          for (int e=0;e<8;e++){
            ug[e] = (tt+e>0) ? u[e] : (unsigned short)0;
            ul[e] = (tt+e<0) ? u[e] : (unsigned short)0;
          }
          bf16x8 ag = __builtin_bit_cast(bf16x8, ug), al = __builtin_bit_cast(bf16x8, ul);
          acc[fi][0]=mfma16(ag,bg0,acc[fi][0]); acc[fi][1]=mfma16(ag,bg1,acc[fi][1]);
          acc[fi][0]=mfma16(al,bl0,acc[fi][0]); acc[fi][1]=mfma16(al,bl1,acc[fi][1]);
        }
      }
    }
    if constexpr (MODE==0){
      const bf16* Bgl = GT + (size_t)h*128*64;
      #pragma unroll
      for (int kt=0;kt<2;kt++){
        const int k0 = kt*32;
        bf16x8 b0 = ldf(Bgl + (size_t)(c0+lr)*64    + k0 + kg*8);
        bf16x8 b1 = ldf(Bgl + (size_t)(c0+16+lr)*64 + k0 + kg*8);
        #pragma unroll
        for (int fi=0;fi<2;fi++){
          bf16x8 a = ldf(A0 + (size_t)(r0+fi*16+lr)*SW + 256 + k0 + kg*8);
          acc[fi][0]=mfma16(a,b0,acc[fi][0]); acc[fi][1]=mfma16(a,b1,acc[fi][1]);
        }
      }
    }
  }
  #pragma unroll
  for (int fi=0;fi<2;fi++)
    #pragma unroll
    for (int fj=0;fj<2;fj++)
      #pragma unroll
      for (int r=0;r<4;r++){
        int row = r0 + fi*16 + kg*4 + r;
        int col = c0 + fj*16 + lr;
        float* d = Mp + ((size_t)hg*BN + b*256 + row)*128 + col;
        if constexpr (MODE==1) *d += acc[fi][fj][r]; else *d = acc[fi][fj][r];
      }
}

// ---- out = x + sum_g Mp[g]; also emit qz = softmax(out) for next iter -------
__global__ __launch_bounds__(256) void k_redqz(const float* __restrict__ x,
                                               const float* __restrict__ Mp,
                                               float* __restrict__ out,
                                               bf16* __restrict__ qzb){
  const int row = blockIdx.x*4 + (threadIdx.x>>6);
  const int lane = threadIdx.x&63;
  const size_t base = (size_t)row*128;
  float v0 = x[base + lane], v1 = x[base + 64 + lane];
  #pragma unroll
  for (int g=0;g<4;g++){
    v0 += Mp[(size_t)g*524288 + base + lane];
    v1 += Mp[(size_t)g*524288 + base + 64 + lane];
  }
  out[base + lane] = v0; out[base + 64 + lane] = v1;
  float m = fmaxf(v0, v1);
  #pragma unroll
  for (int o=32;o;o>>=1) m = fmaxf(m, __shfl_xor(m, o));
  float e0 = __expf(v0-m), e1 = __expf(v1-m), s = e0+e1;
  #pragma unroll
  for (int o=32;o;o>>=1) s += __shfl_xor(s, o);
  float inv = 1.f/s;
  qzb[base + lane] = f2b(e0*inv); qzb[base + 64 + lane] = f2b(e1*inv);
}

// -----------------------------------------------------------------------------
extern "C" void kernel_launch(void* const* d_in, const int* in_sizes, int n_in,
                              void* d_out, int out_size, void* d_ws, size_t ws_size,
                              hipStream_t stream) {
  (void)in_sizes; (void)n_in; (void)out_size; (void)ws_size;
  const float* x    = (const float*)d_in[0];
  const int*   mask = (const int*)d_in[1];
  const float* tern = (const float*)d_in[2];
  const float* glb  = (const float*)d_in[3];
  float* out = (float*)d_out;

  char* w = (char*)d_ws;
  auto alloc = [&](size_t bytes){ void* p = (void*)w; w += (bytes + 255) & ~(size_t)255; return p; };
  bf16* qzb   = (bf16*) alloc((size_t)BN*128*2);            // 1 MB
  bf16* left  = (bf16*) alloc((size_t)16*BN*128*2);         // 16.8 MB
  bf16* LT2   = (bf16*) alloc((size_t)16*16*128*256*2);     // 16.8 MB
  bf16* RT2   = (bf16*) alloc((size_t)16*16*128*256*2);     // 16.8 MB
  bf16* S     = (bf16*) alloc((size_t)128*256*SW*2);        // 21 MB
  bf16* qh    = (bf16*) alloc((size_t)128*256*SW*2);        // 21 MB
  bf16* qhT2  = (bf16*) alloc((size_t)128*4*256*64*2);      // 16.8 MB
  float* Mp   = (float*)alloc((size_t)4*BN*128*4);          // 8.4 MB
  bf16* TL    = (bf16*) alloc((size_t)16*128*128*2);
  bf16* TR    = (bf16*) alloc((size_t)16*128*128*2);
  bf16* GB    = (bf16*) alloc((size_t)8*64*128*2);
  bf16* GT    = (bf16*) alloc((size_t)8*64*128*2);

  k_prep<<<1024, 256, 0, stream>>>(tern, glb, TL, TR, GB, GT);
  k_softmax_qz<<<1024, 256, 0, stream>>>(x, qzb);

  for (int it = 0; it < 4; ++it){
    k_proj<<<dim3(64,2,32), 256, 0, stream>>>(qzb, TL, TR, left, LT2, RT2);
    k_FS<<<dim3(4,5,128), 256, 0, stream>>>(qzb, left, GB, mask, S);
    k_softmax_T<<<dim3(4,128), 256, 0, stream>>>(S, qh, qhT2);
    k_M<0><<<dim3(4,2,64), 256, 0, stream>>>(qh, RT2, RT2 + KOFF, GT, Mp);
    k_M<1><<<dim3(4,2,64), 256, 0, stream>>>(qhT2, LT2 + KOFF, LT2, GT, Mp);
    k_redqz<<<1024, 256, 0, stream>>>(x, Mp, out, qzb);
  }
}

// Round 5
// 550.962 us; speedup vs baseline: 4.0140x; 1.2272x over previous
//
#include <hip/hip_runtime.h>
#include <hip/hip_bf16.h>

using bf16 = __hip_bfloat16;
typedef __bf16 bf16x8 __attribute__((ext_vector_type(8)));
typedef float f32x4 __attribute__((ext_vector_type(4)));
typedef unsigned short u16x8 __attribute__((ext_vector_type(8)));
typedef unsigned short u16x4 __attribute__((ext_vector_type(4)));

constexpr int B_ = 16, H_ = 8;
constexpr int BN = 4096;            // B_*N_
constexpr int SW = 320;             // N_+G_
constexpr float FNEG = -1000000000.0f;
constexpr size_t KOFF = (size_t)8 * 16 * 128 * 256;   // k-plane stride in RT2/LT2

__device__ __forceinline__ float b2f(bf16 v){ return __bfloat162float(v); }
__device__ __forceinline__ bf16 f2b(float v){ return __float2bfloat16(v); }
__device__ __forceinline__ bf16x8 ldf(const bf16* p){ return *(const bf16x8*)p; }
__device__ __forceinline__ f32x4 mfma16(bf16x8 a, bf16x8 b, f32x4 c){
  return __builtin_amdgcn_mfma_f32_16x16x32_bf16(a, b, c, 0, 0, 0);
}

// ---- one-time: permute ternary/global_ into bf16 B^T layouts ----------------
__global__ __launch_bounds__(256) void k_prep(const float* __restrict__ tern,
                                              const float* __restrict__ glb,
                                              bf16* __restrict__ TL, bf16* __restrict__ TR,
                                              bf16* __restrict__ GB, bf16* __restrict__ GT){
  int t = blockIdx.x*256 + threadIdx.x;        // 0..262143
  {
    int kh = t>>14, rest = t&16383;
    int k = kh>>3, h = kh&7;
    int r = rest>>7, cc = rest&127;
    TL[t] = f2b(tern[(((size_t)k*128 + cc)*128 + r)*8 + h]);   // TL[kh][c][a]
    TR[t] = f2b(tern[(((size_t)k*128 + r)*128 + cc)*8 + h]);   // TR[kh][a][c]
  }
  if (t < 65536){
    int h = t>>13, rest = t&8191;
    { int g = rest>>7, a = rest&127;   // GB[h][g][a]
      GB[t] = f2b(glb[((size_t)g*128 + a)*8 + h]); }
    { int a = rest>>6, g = rest&63;    // GT[h][a][g]
      GT[t] = f2b(glb[((size_t)g*128 + a)*8 + h]); }
  }
}

// ---- it0: qz = softmax(x, -1) ------------------------------------------------
__global__ __launch_bounds__(256) void k_softmax_qz(const float* __restrict__ Q,
                                                    bf16* __restrict__ qzb){
  int row = blockIdx.x*4 + (threadIdx.x>>6);
  int lane = threadIdx.x&63;
  const float* q = Q + (size_t)row*128;
  float v0 = q[lane], v1 = q[lane+64];
  float m = fmaxf(v0, v1);
  #pragma unroll
  for (int o=32;o;o>>=1) m = fmaxf(m, __shfl_xor(m, o));
  float e0 = __expf(v0-m), e1 = __expf(v1-m), s = e0+e1;
  #pragma unroll
  for (int o=32;o;o>>=1) s += __shfl_xor(s, o);
  float inv = 1.f/s;
  bf16* o_ = qzb + (size_t)row*128;
  o_[lane] = f2b(e0*inv); o_[lane+64] = f2b(e1*inv);
}

// ---- proj (merged L/R): left[kh][bi][c] + LT2/RT2 blocked-transposed --------
__global__ __launch_bounds__(256) void k_proj(const bf16* __restrict__ qzb,
                                              const bf16* __restrict__ TL,
                                              const bf16* __restrict__ TR,
                                              bf16* __restrict__ left,
                                              bf16* __restrict__ LT2,
                                              bf16* __restrict__ RT2){
  const int z = blockIdx.z; const int kh = z & 15; const bool rightP = z >= 16;
  const int wi = threadIdx.x>>7, wj = (threadIdx.x>>6)&1;
  const int lane = threadIdx.x&63, lr = lane&15, kg = lane>>4;
  const int rb0 = blockIdx.x*64, cb = blockIdx.y*64;
  const int r0 = rb0 + wi*32, c0 = cb + wj*32;
  const bf16* A  = qzb + (size_t)r0*128;
  const bf16* Bb = (rightP ? TR : TL) + ((size_t)kh*128 + c0)*128;
  f32x4 acc[2][2] = {};
  #pragma unroll
  for (int k0=0;k0<128;k0+=32){
    bf16x8 a0 = ldf(A  + (size_t)lr*128      + k0 + kg*8);
    bf16x8 a1 = ldf(A  + (size_t)(lr+16)*128 + k0 + kg*8);
    bf16x8 b0 = ldf(Bb + (size_t)lr*128      + k0 + kg*8);
    bf16x8 b1 = ldf(Bb + (size_t)(lr+16)*128 + k0 + kg*8);
    acc[0][0]=mfma16(a0,b0,acc[0][0]); acc[0][1]=mfma16(a0,b1,acc[0][1]);
    acc[1][0]=mfma16(a1,b0,acc[1][0]); acc[1][1]=mfma16(a1,b1,acc[1][1]);
  }
  __shared__ unsigned short tl[64][68];
  #pragma unroll
  for (int fi=0;fi<2;fi++)
    #pragma unroll
    for (int fj=0;fj<2;fj++){
      u16x4 pk;
      #pragma unroll
      for (int r=0;r<4;r++) pk[r] = __builtin_bit_cast(unsigned short, f2b(acc[fi][fj][r]));
      *(u16x4*)&tl[wj*32 + fj*16 + lr][wi*32 + fi*16 + kg*4] = pk;
    }
  if (!rightP){
    #pragma unroll
    for (int fi=0;fi<2;fi++){
      int rb = r0 + fi*16 + kg*4;
      #pragma unroll
      for (int fj=0;fj<2;fj++){
        int col = c0 + fj*16 + lr;
        #pragma unroll
        for (int r=0;r<4;r++)
          left[((size_t)kh*BN + rb + r)*128 + col] = f2b(acc[fi][fj][r]);
      }
    }
  }
  __syncthreads();
  const int b = rb0 >> 8, jloc = rb0 & 255;
  const int col = threadIdx.x >> 2, seg = threadIdx.x & 3;
  bf16* O = rightP ? RT2 : LT2;
  unsigned short* dst = (unsigned short*)O +
      (((size_t)kh*16 + b)*128 + cb + col)*256 + jloc + seg*16;
  const unsigned short* src = &tl[col][seg*16];
  #pragma unroll
  for (int e=0;e<4;e++) *(u16x4*)(dst + e*4) = *(const u16x4*)(src + e*4);
}

// ---- fused: S-row (F+bias | Gs) -> softmax -> qh + qhT2 ---------------------
// block: 4 waves; wave w owns rows iw..iw+15 (all 320 cols). grid (4, 128).
__global__ __launch_bounds__(256) void k_FSM(const bf16* __restrict__ qzb,
                                             const bf16* __restrict__ left,
                                             const bf16* __restrict__ GB,
                                             const int* __restrict__ mask,
                                             bf16* __restrict__ qh,
                                             bf16* __restrict__ qhT2){
  const int bh = blockIdx.y, b = bh>>3, h = bh&7;
  const int ib4 = blockIdx.x;
  const int w = threadIdx.x>>6, lane = threadIdx.x&63;
  const int lr = lane&15, kg = lane>>4;
  const int i0 = ib4*64, iw = i0 + w*16;
  const int fd = iw>>4;                      // diagonal j-fragment index
  const bf16* qzB = qzb + (size_t)b*256*128;
  const bf16* L0 = left + ((size_t)h*BN     + b*256 + iw)*128;
  const bf16* L1 = left + ((size_t)(8+h)*BN + b*256 + iw)*128;
  const bf16* GBh = GB + (size_t)h*64*128;
  f32x4 acc[20] = {}; f32x4 accD = {};
  #pragma unroll
  for (int k0=0;k0<128;k0+=32){
    bf16x8 aQ  = ldf(qzB + (size_t)(iw+lr)*128 + k0 + kg*8);
    bf16x8 aL0 = ldf(L0 + (size_t)lr*128 + k0 + kg*8);
    bf16x8 aL1 = ldf(L1 + (size_t)lr*128 + k0 + kg*8);
    #pragma unroll
    for (int f=0;f<16;f++){
      bf16x8 bf_ = ldf(qzB + (size_t)(f*16+lr)*128 + k0 + kg*8);
      acc[f] = mfma16((f>=fd)? aL0 : aL1, bf_, acc[f]);
      if (f==fd) accD = mfma16(aL1, bf_, accD);
    }
    #pragma unroll
    for (int f2=0;f2<4;f2++){
      bf16x8 bg = ldf(GBh + (size_t)(f2*16+lr)*128 + k0 + kg*8);
      acc[16+f2] = mfma16(aQ, bg, acc[16+f2]);
    }
  }
  // select + bias + row-softmax (rows live as: row = iw + kg*4 + r, col = f*16+lr)
  const int* mb = mask + b*256;
  int mi[4];
  #pragma unroll
  for (int r=0;r<4;r++) mi[r] = mb[iw + kg*4 + r];
  float m[4] = {-3e38f,-3e38f,-3e38f,-3e38f};
  #pragma unroll
  for (int f=0;f<20;f++){
    if (f<16){
      int mj = mb[f*16 + lr];
      #pragma unroll
      for (int r=0;r<4;r++){
        float v = acc[f][r];
        if (f==fd){
          int d = lr - (kg*4+r);
          v = d>0 ? acc[f][r] : (d<0 ? accD[r] : 0.f);
        }
        v += (mi[r] && mj) ? 0.f : FNEG;
        acc[f][r] = v;
        m[r] = fmaxf(m[r], v);
      }
    } else {
      #pragma unroll
      for (int r=0;r<4;r++) m[r] = fmaxf(m[r], acc[f][r]);
    }
  }
  #pragma unroll
  for (int o=1;o<16;o<<=1)
    #pragma unroll
    for (int r=0;r<4;r++) m[r] = fmaxf(m[r], __shfl_xor(m[r], o));
  float s[4] = {0.f,0.f,0.f,0.f};
  #pragma unroll
  for (int f=0;f<20;f++)
    #pragma unroll
    for (int r=0;r<4;r++){ float e = __expf(acc[f][r]-m[r]); acc[f][r]=e; s[r]+=e; }
  #pragma unroll
  for (int o=1;o<16;o<<=1)
    #pragma unroll
    for (int r=0;r<4;r++) s[r] += __shfl_xor(s[r], o);
  float inv[4];
  #pragma unroll
  for (int r=0;r<4;r++) inv[r] = 1.f/s[r];
  // transpose-stage in LDS: t2[col(320)][row-in-64]
  __shared__ unsigned short t2[320][72];
  const int rowb = w*16 + kg*4;
  #pragma unroll
  for (int f=0;f<20;f++){
    u16x4 pk;
    #pragma unroll
    for (int r=0;r<4;r++) pk[r] = __builtin_bit_cast(unsigned short, f2b(acc[f][r]*inv[r]));
    *(u16x4*)&t2[f*16+lr][rowb] = pk;
  }
  __syncthreads();
  { // qhT2[bh][ib4][j][i64] — contiguous both sides
    const int j = threadIdx.x;
    unsigned short* dst = (unsigned short*)qhT2 + (((size_t)bh*4 + ib4)*256 + j)*64;
    #pragma unroll
    for (int e0=0;e0<64;e0+=8) *(u16x8*)(dst+e0) = *(const u16x8*)&t2[j][e0];
  }
  { // qh rows (stride 320)
    const int row = threadIdx.x&63, seg = threadIdx.x>>6;
    unsigned short* dst = (unsigned short*)qh + ((size_t)bh*256 + i0 + row)*SW + seg*80;
    #pragma unroll
    for (int cc=0;cc<10;cc++){
      u16x8 pk;
      #pragma unroll
      for (int e=0;e<8;e++) pk[e] = t2[seg*80 + cc*8 + e][row];
      *(u16x8*)(dst + cc*8) = pk;
    }
  }
}

// ---- merged M1(+MG) / M2, 2 h per block, separate Mp planes -----------------
// z: 0..63 -> mode0 (M1+MG, A=qh), 64..127 -> mode1 (M2, A=qhT2)
__global__ __launch_bounds__(256) void k_M2x(const bf16* __restrict__ qh,
                                             const bf16* __restrict__ qhT2,
                                             const bf16* __restrict__ RT2,
                                             const bf16* __restrict__ LT2,
                                             const bf16* __restrict__ GT,
                                             float* __restrict__ Mp){
  const int z = blockIdx.z;
  const int mode = z>>6, zz = z&63, b = zz>>2, hg = zz&3;
  const int wi = threadIdx.x>>7, wj = (threadIdx.x>>6)&1;
  const int lane = threadIdx.x&63, lr = lane&15, kg = lane>>4;
  const int r0 = blockIdx.x*64 + wi*32;
  const int c0 = blockIdx.y*64 + wj*32;
  f32x4 acc[2][2] = {};
  #pragma unroll
  for (int hh=0;hh<2;hh++){
    const int h = hg*2 + hh;
    const bf16* Bg = (mode ? LT2+KOFF : RT2) + ((size_t)h*16 + b)*128*256;
    const bf16* Bl = (mode ? LT2 : RT2+KOFF) + ((size_t)h*16 + b)*128*256;
    const bf16* A0 = mode ? qhT2 + (size_t)(b*8+h)*65536
                          : qh   + (size_t)(b*8+h)*256*SW;
    #pragma unroll
    for (int kt=0;kt<8;kt++){
      const int k0 = kt*32;
      const bool needG = (k0 >= r0), needL = (k0 <= r0+32);
      bf16x8 bg0{}, bg1{}, bl0{}, bl1{};
      if (needG){
        bg0 = ldf(Bg + (size_t)(c0+lr)*256    + k0 + kg*8);
        bg1 = ldf(Bg + (size_t)(c0+16+lr)*256 + k0 + kg*8);
      }
      if (needL){
        bl0 = ldf(Bl + (size_t)(c0+lr)*256    + k0 + kg*8);
        bl1 = ldf(Bl + (size_t)(c0+16+lr)*256 + k0 + kg*8);
      }
      #pragma unroll
      for (int fi=0;fi<2;fi++){
        const int ib = r0 + fi*16;
        bf16x8 a = (mode==0)
          ? ldf(A0 + (size_t)(ib+lr)*SW + k0 + kg*8)
          : ldf(A0 + (((size_t)(k0>>6))*256 + ib + lr)*64 + (k0&63) + kg*8);
        if (k0 >= ib + 16){
          acc[fi][0]=mfma16(a,bg0,acc[fi][0]); acc[fi][1]=mfma16(a,bg1,acc[fi][1]);
        } else if (k0 + 32 <= ib){
          acc[fi][0]=mfma16(a,bl0,acc[fi][0]); acc[fi][1]=mfma16(a,bl1,acc[fi][1]);
        } else {
          u16x8 u = __builtin_bit_cast(u16x8, a), ug, ul;
          const int tt = k0 + kg*8 - ib - lr;
          #pragma unroll
          for (int e=0;e<8;e++){
            ug[e] = (tt+e>0) ? u[e] : (unsigned short)0;
            ul[e] = (tt+e<0) ? u[e] : (unsigned short)0;
          }
          bf16x8 ag = __builtin_bit_cast(bf16x8, ug), al = __builtin_bit_cast(bf16x8, ul);
          acc[fi][0]=mfma16(ag,bg0,acc[fi][0]); acc[fi][1]=mfma16(ag,bg1,acc[fi][1]);
          acc[fi][0]=mfma16(al,bl0,acc[fi][0]); acc[fi][1]=mfma16(al,bl1,acc[fi][1]);
        }
      }
    }
    if (mode==0){
      const bf16* Bgl = GT + (size_t)h*128*64;
      #pragma unroll
      for (int kt=0;kt<2;kt++){
        const int k0 = kt*32;
        bf16x8 b0 = ldf(Bgl + (size_t)(c0+lr)*64    + k0 + kg*8);
        bf16x8 b1 = ldf(Bgl + (size_t)(c0+16+lr)*64 + k0 + kg*8);
        #pragma unroll
        for (int fi=0;fi<2;fi++){
          bf16x8 a = ldf(A0 + (size_t)(r0+fi*16+lr)*SW + 256 + k0 + kg*8);
          acc[fi][0]=mfma16(a,b0,acc[fi][0]); acc[fi][1]=mfma16(a,b1,acc[fi][1]);
        }
      }
    }
  }
  const int plane = mode*4 + hg;
  #pragma unroll
  for (int fi=0;fi<2;fi++)
    #pragma unroll
    for (int fj=0;fj<2;fj++)
      #pragma unroll
      for (int r=0;r<4;r++){
        int row = r0 + fi*16 + kg*4 + r;
        int col = c0 + fj*16 + lr;
        Mp[((size_t)plane*BN + b*256 + row)*128 + col] = acc[fi][fj][r];
      }
}

// ---- out = x + sum_p Mp[p]; emit qz = softmax(out) for next iter ------------
__global__ __launch_bounds__(256) void k_redqz(const float* __restrict__ x,
                                               const float* __restrict__ Mp,
                                               float* __restrict__ out,
                                               bf16* __restrict__ qzb){
  const int row = blockIdx.x*4 + (threadIdx.x>>6);
  const int lane = threadIdx.x&63;
  const size_t base = (size_t)row*128;
  float v0 = x[base + lane], v1 = x[base + 64 + lane];
  #pragma unroll
  for (int g=0;g<8;g++){
    v0 += Mp[(size_t)g*524288 + base + lane];
    v1 += Mp[(size_t)g*524288 + base + 64 + lane];
  }
  out[base + lane] = v0; out[base + 64 + lane] = v1;
  float m = fmaxf(v0, v1);
  #pragma unroll
  for (int o=32;o;o>>=1) m = fmaxf(m, __shfl_xor(m, o));
  float e0 = __expf(v0-m), e1 = __expf(v1-m), s = e0+e1;
  #pragma unroll
  for (int o=32;o;o>>=1) s += __shfl_xor(s, o);
  float inv = 1.f/s;
  qzb[base + lane] = f2b(e0*inv); qzb[base + 64 + lane] = f2b(e1*inv);
}

// -----------------------------------------------------------------------------
extern "C" void kernel_launch(void* const* d_in, const int* in_sizes, int n_in,
                              void* d_out, int out_size, void* d_ws, size_t ws_size,
                              hipStream_t stream) {
  (void)in_sizes; (void)n_in; (void)out_size; (void)ws_size;
  const float* x    = (const float*)d_in[0];
  const int*   mask = (const int*)d_in[1];
  const float* tern = (const float*)d_in[2];
  const float* glb  = (const float*)d_in[3];
  float* out = (float*)d_out;

  char* w = (char*)d_ws;
  auto alloc = [&](size_t bytes){ void* p = (void*)w; w += (bytes + 255) & ~(size_t)255; return p; };
  bf16* qzb   = (bf16*) alloc((size_t)BN*128*2);            // 1 MB
  bf16* left  = (bf16*) alloc((size_t)16*BN*128*2);         // 16.8 MB
  bf16* LT2   = (bf16*) alloc((size_t)16*16*128*256*2);     // 16.8 MB
  bf16* RT2   = (bf16*) alloc((size_t)16*16*128*256*2);     // 16.8 MB
  bf16* qh    = (bf16*) alloc((size_t)128*256*SW*2);        // 21 MB
  bf16* qhT2  = (bf16*) alloc((size_t)128*4*256*64*2);      // 16.8 MB
  float* Mp   = (float*)alloc((size_t)8*BN*128*4);          // 16.8 MB
  bf16* TL    = (bf16*) alloc((size_t)16*128*128*2);
  bf16* TR    = (bf16*) alloc((size_t)16*128*128*2);
  bf16* GB    = (bf16*) alloc((size_t)8*64*128*2);
  bf16* GT    = (bf16*) alloc((size_t)8*64*128*2);

  k_prep<<<1024, 256, 0, stream>>>(tern, glb, TL, TR, GB, GT);
  k_softmax_qz<<<1024, 256, 0, stream>>>(x, qzb);

  for (int it = 0; it < 4; ++it){
    k_proj<<<dim3(64,2,32), 256, 0, stream>>>(qzb, TL, TR, left, LT2, RT2);
    k_FSM<<<dim3(4,128), 256, 0, stream>>>(qzb, left, GB, mask, qh, qhT2);
    k_M2x<<<dim3(4,2,128), 256, 0, stream>>>(qh, qhT2, RT2, LT2, GT, Mp);
    k_redqz<<<1024, 256, 0, stream>>>(x, Mp, out, qzb);
  }
}

// Round 8
// 545.933 us; speedup vs baseline: 4.0510x; 1.0092x over previous
//
#include <hip/hip_runtime.h>
#include <hip/hip_bf16.h>

using bf16 = __hip_bfloat16;
typedef __bf16 bf16x8 __attribute__((ext_vector_type(8)));
typedef float f32x4 __attribute__((ext_vector_type(4)));
typedef unsigned short u16x8 __attribute__((ext_vector_type(8)));
typedef unsigned short u16x4 __attribute__((ext_vector_type(4)));

constexpr int B_ = 16, H_ = 8;
constexpr int BN = 4096;            // B_*N_
constexpr int SW = 320;             // N_+G_
constexpr float FNEG = -1000000000.0f;
constexpr size_t KOFF = (size_t)8 * 16 * 128 * 256;   // k-plane stride in RT2/LT2

__device__ __forceinline__ float b2f(bf16 v){ return __bfloat162float(v); }
__device__ __forceinline__ bf16 f2b(float v){ return __float2bfloat16(v); }
__device__ __forceinline__ bf16x8 ldf(const bf16* p){ return *(const bf16x8*)p; }
__device__ __forceinline__ f32x4 mfma16(bf16x8 a, bf16x8 b, f32x4 c){
  return __builtin_amdgcn_mfma_f32_16x16x32_bf16(a, b, c, 0, 0, 0);
}

// ---- one-time: permute ternary/global_ into bf16 B^T layouts ----------------
__global__ __launch_bounds__(256) void k_prep(const float* __restrict__ tern,
                                              const float* __restrict__ glb,
                                              bf16* __restrict__ TL, bf16* __restrict__ TR,
                                              bf16* __restrict__ GB, bf16* __restrict__ GT){
  int t = blockIdx.x*256 + threadIdx.x;        // 0..262143
  {
    int kh = t>>14, rest = t&16383;
    int k = kh>>3, h = kh&7;
    int r = rest>>7, cc = rest&127;
    TL[t] = f2b(tern[(((size_t)k*128 + cc)*128 + r)*8 + h]);   // TL[kh][c][a]
    TR[t] = f2b(tern[(((size_t)k*128 + r)*128 + cc)*8 + h]);   // TR[kh][a][c]
  }
  if (t < 65536){
    int h = t>>13, rest = t&8191;
    { int g = rest>>7, a = rest&127;   // GB[h][g][a]
      GB[t] = f2b(glb[((size_t)g*128 + a)*8 + h]); }
    { int a = rest>>6, g = rest&63;    // GT[h][a][g]
      GT[t] = f2b(glb[((size_t)g*128 + a)*8 + h]); }
  }
}

// ---- it0: qz = softmax(x, -1) ------------------------------------------------
__global__ __launch_bounds__(256) void k_softmax_qz(const float* __restrict__ Q,
                                                    bf16* __restrict__ qzb){
  int row = blockIdx.x*4 + (threadIdx.x>>6);
  int lane = threadIdx.x&63;
  const float* q = Q + (size_t)row*128;
  float v0 = q[lane], v1 = q[lane+64];
  float m = fmaxf(v0, v1);
  #pragma unroll
  for (int o=32;o;o>>=1) m = fmaxf(m, __shfl_xor(m, o));
  float e0 = __expf(v0-m), e1 = __expf(v1-m), s = e0+e1;
  #pragma unroll
  for (int o=32;o;o>>=1) s += __shfl_xor(s, o);
  float inv = 1.f/s;
  bf16* o_ = qzb + (size_t)row*128;
  o_[lane] = f2b(e0*inv); o_[lane+64] = f2b(e1*inv);
}

// ---- proj (merged L/R): left[kh][bi][c] + LT2/RT2 blocked-transposed --------
// 1-D grid 4096, chunked XCD swizzle (4 kh-passes per XCD).
__global__ __launch_bounds__(256) void k_proj(const bf16* __restrict__ qzb,
                                              const bf16* __restrict__ TL,
                                              const bf16* __restrict__ TR,
                                              bf16* __restrict__ left,
                                              bf16* __restrict__ LT2,
                                              bf16* __restrict__ RT2){
  const int id = blockIdx.x;
  const int swz = (id & 7)*512 + (id >> 3);   // chunked: XCD c gets 512 consecutive
  const int bx = swz & 63, by = (swz >> 6) & 1, z = swz >> 7;
  const int kh = z & 15; const bool rightP = z >= 16;
  const int wi = threadIdx.x>>7, wj = (threadIdx.x>>6)&1;
  const int lane = threadIdx.x&63, lr = lane&15, kg = lane>>4;
  const int rb0 = bx*64, cb = by*64;
  const int r0 = rb0 + wi*32, c0 = cb + wj*32;
  const bf16* A  = qzb + (size_t)r0*128;
  const bf16* Bb = (rightP ? TR : TL) + ((size_t)kh*128 + c0)*128;
  f32x4 acc[2][2] = {};
  #pragma unroll
  for (int k0=0;k0<128;k0+=32){
    bf16x8 a0 = ldf(A  + (size_t)lr*128      + k0 + kg*8);
    bf16x8 a1 = ldf(A  + (size_t)(lr+16)*128 + k0 + kg*8);
    bf16x8 b0 = ldf(Bb + (size_t)lr*128      + k0 + kg*8);
    bf16x8 b1 = ldf(Bb + (size_t)(lr+16)*128 + k0 + kg*8);
    acc[0][0]=mfma16(a0,b0,acc[0][0]); acc[0][1]=mfma16(a0,b1,acc[0][1]);
    acc[1][0]=mfma16(a1,b0,acc[1][0]); acc[1][1]=mfma16(a1,b1,acc[1][1]);
  }
  __shared__ unsigned short tl[64][68];      // [col][row]
  #pragma unroll
  for (int fi=0;fi<2;fi++)
    #pragma unroll
    for (int fj=0;fj<2;fj++){
      u16x4 pk;
      #pragma unroll
      for (int r=0;r<4;r++) pk[r] = __builtin_bit_cast(unsigned short, f2b(acc[fi][fj][r]));
      *(u16x4*)&tl[wj*32 + fj*16 + lr][wi*32 + fi*16 + kg*4] = pk;
    }
  __syncthreads();
  const int tt = threadIdx.x;
  { // LT2/RT2 blocked-transposed store: [kh*16+b][col][K-local 256]
    const int b = rb0 >> 8, jloc = rb0 & 255;
    const int col = tt >> 2, seg = tt & 3;
    bf16* O = rightP ? RT2 : LT2;
    unsigned short* dst = (unsigned short*)O +
        (((size_t)kh*16 + b)*128 + cb + col)*256 + jloc + seg*16;
    const unsigned short* src = &tl[col][seg*16];
    #pragma unroll
    for (int e=0;e<4;e++) *(u16x4*)(dst + e*4) = *(const u16x4*)(src + e*4);
  }
  if (!rightP){ // row-major left store, coalesced via LDS
    const int row = tt & 63, cseg = tt >> 6;
    u16x8 p0, p1;
    #pragma unroll
    for (int e=0;e<8;e++) p0[e] = tl[cseg*16+e][row];
    #pragma unroll
    for (int e=0;e<8;e++) p1[e] = tl[cseg*16+8+e][row];
    unsigned short* dst = (unsigned short*)left +
        ((size_t)kh*BN + rb0 + row)*128 + cb + cseg*16;
    *(u16x8*)dst = p0; *(u16x8*)(dst+8) = p1;
  }
}

// ---- fused: S-row (F+bias | Gs) -> softmax -> qh + qhT2 ---------------------
// 1-D grid 512 (chunk-swizzled). 4 waves/block, wave owns 16 rows × all 320.
// qz B-fragments come from a 2×16KB LDS double-buffer (T14 staging).
__global__ __launch_bounds__(256) void k_FSM(const bf16* __restrict__ qzb,
                                             const bf16* __restrict__ left,
                                             const bf16* __restrict__ GB,
                                             const int* __restrict__ mask,
                                             bf16* __restrict__ qh,
                                             bf16* __restrict__ qhT2){
  const int id = blockIdx.x;
  const int swz = (id & 7)*64 + (id >> 3);    // 16 bh per XCD
  const int ib4 = swz & 3, bh = swz >> 2;
  const int b = bh>>3, h = bh&7;
  const int w = threadIdx.x>>6, lane = threadIdx.x&63;
  const int lr = lane&15, kg = lane>>4;
  const int i0 = ib4*64, iw = i0 + w*16;
  const int fd = iw>>4;                      // diagonal j-fragment index
  const bf16* qzB = qzb + (size_t)b*256*128;
  const bf16* L0 = left + ((size_t)h*BN     + b*256 + iw)*128;
  const bf16* L1 = left + ((size_t)(8+h)*BN + b*256 + iw)*128;
  const bf16* GBh = GB + (size_t)h*64*128;

  __shared__ unsigned short qt[2][8192];     // [256 rows][32 k] halfwords
  __shared__ unsigned short t2[320][72];

  const int tt = threadIdx.x;
  const int sr = tt>>2, sk = (tt&3)*8;       // staging: row base, k offset
  u16x8 rg[4];
  #pragma unroll
  for (int c=0;c<4;c++)
    rg[c] = *(const u16x8*)((const unsigned short*)qzB + (size_t)(c*64+sr)*128 + sk);
  #pragma unroll
  for (int c=0;c<4;c++)
    *(u16x8*)&qt[0][(c*64+sr)*32 + sk] = rg[c];
  __syncthreads();

  f32x4 acc[20] = {}; f32x4 accD = {};
  #pragma unroll
  for (int ks=0; ks<4; ks++){
    const int k0 = ks*32; const int cur = ks&1;
    if (ks<3){
      #pragma unroll
      for (int c=0;c<4;c++)
        rg[c] = *(const u16x8*)((const unsigned short*)qzB + (size_t)(c*64+sr)*128 + k0+32 + sk);
    }
    bf16x8 aQ  = *(const bf16x8*)&qt[cur][(iw+lr)*32 + kg*8];
    bf16x8 aL0 = ldf(L0 + (size_t)lr*128 + k0 + kg*8);
    bf16x8 aL1 = ldf(L1 + (size_t)lr*128 + k0 + kg*8);
    #pragma unroll
    for (int f=0;f<16;f++){
      bf16x8 bf_ = *(const bf16x8*)&qt[cur][(f*16+lr)*32 + kg*8];
      acc[f] = mfma16((f>=fd)? aL0 : aL1, bf_, acc[f]);
      if (f==fd) accD = mfma16(aL1, bf_, accD);
    }
    #pragma unroll
    for (int f2=0;f2<4;f2++){
      bf16x8 bg = ldf(GBh + (size_t)(f2*16+lr)*128 + k0 + kg*8);
      acc[16+f2] = mfma16(aQ, bg, acc[16+f2]);
    }
    if (ks<3){
      #pragma unroll
      for (int c=0;c<4;c++)
        *(u16x8*)&qt[cur^1][(c*64+sr)*32 + sk] = rg[c];
    }
    __syncthreads();
  }
  // select + bias + row-softmax (row = iw + kg*4 + r, col = f*16+lr)
  const int* mb = mask + b*256;
  int mi[4];
  #pragma unroll
  for (int r=0;r<4;r++) mi[r] = mb[iw + kg*4 + r];
  float m[4] = {-3e38f,-3e38f,-3e38f,-3e38f};
  #pragma unroll
  for (int f=0;f<20;f++){
    if (f<16){
      int mj = mb[f*16 + lr];
      #pragma unroll
      for (int r=0;r<4;r++){
        float v = acc[f][r];
        if (f==fd){
          int d = lr - (kg*4+r);
          v = d>0 ? acc[f][r] : (d<0 ? accD[r] : 0.f);
        }
        v += (mi[r] && mj) ? 0.f : FNEG;
        acc[f][r] = v;
        m[r] = fmaxf(m[r], v);
      }
    } else {
      #pragma unroll
      for (int r=0;r<4;r++) m[r] = fmaxf(m[r], acc[f][r]);
    }
  }
  #pragma unroll
  for (int o=1;o<16;o<<=1)
    #pragma unroll
    for (int r=0;r<4;r++) m[r] = fmaxf(m[r], __shfl_xor(m[r], o));
  float s[4] = {0.f,0.f,0.f,0.f};
  #pragma unroll
  for (int f=0;f<20;f++)
    #pragma unroll
    for (int r=0;r<4;r++){ float e = __expf(acc[f][r]-m[r]); acc[f][r]=e; s[r]+=e; }
  #pragma unroll
  for (int o=1;o<16;o<<=1)
    #pragma unroll
    for (int r=0;r<4;r++) s[r] += __shfl_xor(s[r], o);
  float inv[4];
  #pragma unroll
  for (int r=0;r<4;r++) inv[r] = 1.f/s[r];
  const int rowb = w*16 + kg*4;
  #pragma unroll
  for (int f=0;f<20;f++){
    u16x4 pk;
    #pragma unroll
    for (int r=0;r<4;r++) pk[r] = __builtin_bit_cast(unsigned short, f2b(acc[f][r]*inv[r]));
    *(u16x4*)&t2[f*16+lr][rowb] = pk;
  }
  __syncthreads();
  { // qhT2[bh][ib4][j][i64]
    const int j = tt;
    unsigned short* dst = (unsigned short*)qhT2 + (((size_t)bh*4 + ib4)*256 + j)*64;
    #pragma unroll
    for (int e0=0;e0<64;e0+=8) *(u16x8*)(dst+e0) = *(const u16x8*)&t2[j][e0];
  }
  { // qh rows (stride 320)
    const int row = tt&63, seg = tt>>6;
    unsigned short* dst = (unsigned short*)qh + ((size_t)bh*256 + i0 + row)*SW + seg*80;
    #pragma unroll
    for (int cc=0;cc<10;cc++){
      u16x8 pk;
      #pragma unroll
      for (int e=0;e<8;e++) pk[e] = t2[seg*80 + cc*8 + e][row];
      *(u16x8*)(dst + cc*8) = pk;
    }
  }
}

// ---- merged M1(+MG)/M2, per-h, XCD-grouped, 16 Mp planes --------------------
// 1-D grid 2048. Group g=(b,h,mode): its 8 blocks (4 row × 2 col) share one XCD.
__global__ __launch_bounds__(256) void k_M2x(const bf16* __restrict__ qh,
                                             const bf16* __restrict__ qhT2,
                                             const bf16* __restrict__ RT2,
                                             const bf16* __restrict__ LT2,
                                             const bf16* __restrict__ GT,
                                             float* __restrict__ Mp){
  const int P = blockIdx.x;
  const int cx = P & 7, t = P >> 3;
  const int g = cx + ((t >> 3) << 3);        // 0..255
  const int m = t & 7;
  const int mode = g & 1, h = (g >> 1) & 7, b = g >> 4;
  const int wi = threadIdx.x>>7, wj = (threadIdx.x>>6)&1;
  const int lane = threadIdx.x&63, lr = lane&15, kg = lane>>4;
  const int r0 = (m & 3)*64 + wi*32;
  const int c0 = (m >> 2)*64 + wj*32;
  const bf16* Bg = (mode ? LT2+KOFF : RT2) + ((size_t)h*16 + b)*128*256;
  const bf16* Bl = (mode ? LT2 : RT2+KOFF) + ((size_t)h*16 + b)*128*256;
  const bf16* A0 = mode ? qhT2 + (size_t)(b*8+h)*65536
                        : qh   + (size_t)(b*8+h)*256*SW;
  f32x4 acc[2][2] = {};
  #pragma unroll
  for (int kt=0;kt<8;kt++){
    const int k0 = kt*32;
    const bool needG = (k0 >= r0), needL = (k0 <= r0+32);
    bf16x8 bg0{}, bg1{}, bl0{}, bl1{};
    if (needG){
      bg0 = ldf(Bg + (size_t)(c0+lr)*256    + k0 + kg*8);
      bg1 = ldf(Bg + (size_t)(c0+16+lr)*256 + k0 + kg*8);
    }
    if (needL){
      bl0 = ldf(Bl + (size_t)(c0+lr)*256    + k0 + kg*8);
      bl1 = ldf(Bl + (size_t)(c0+16+lr)*256 + k0 + kg*8);
    }
    #pragma unroll
    for (int fi=0;fi<2;fi++){
      const int ib = r0 + fi*16;
      bf16x8 a = (mode==0)
        ? ldf(A0 + (size_t)(ib+lr)*SW + k0 + kg*8)
        : ldf(A0 + (((size_t)(k0>>6))*256 + ib + lr)*64 + (k0&63) + kg*8);
      if (k0 >= ib + 16){
        acc[fi][0]=mfma16(a,bg0,acc[fi][0]); acc[fi][1]=mfma16(a,bg1,acc[fi][1]);
      } else if (k0 + 32 <= ib){
        acc[fi][0]=mfma16(a,bl0,acc[fi][0]); acc[fi][1]=mfma16(a,bl1,acc[fi][1]);
      } else {
        u16x8 u = __builtin_bit_cast(u16x8, a), ug, ul;
        const int d0 = k0 + kg*8 - ib - lr;
        #pragma unroll
        for (int e=0;e<8;e++){
          ug[e] = (d0+e>0) ? u[e] : (unsigned short)0;
          ul[e] = (d0+e<0) ? u[e] : (unsigned short)0;
        }
        bf16x8 ag = __builtin_bit_cast(bf16x8, ug), al = __builtin_bit_cast(bf16x8, ul);
        acc[fi][0]=mfma16(ag,bg0,acc[fi][0]); acc[fi][1]=mfma16(ag,bg1,acc[fi][1]);
        acc[fi][0]=mfma16(al,bl0,acc[fi][0]); acc[fi][1]=mfma16(al,bl1,acc[fi][1]);
      }
    }
  }
  if (mode==0){
    const bf16* Bgl = GT + (size_t)h*128*64;
    #pragma unroll
    for (int kt=0;kt<2;kt++){
      const int k0 = kt*32;
      bf16x8 b0 = ldf(Bgl + (size_t)(c0+lr)*64    + k0 + kg*8);
      bf16x8 b1 = ldf(Bgl + (size_t)(c0+16+lr)*64 + k0 + kg*8);
      #pragma unroll
      for (int fi=0;fi<2;fi++){
        bf16x8 a = ldf(A0 + (size_t)(r0+fi*16+lr)*SW + 256 + k0 + kg*8);
        acc[fi][0]=mfma16(a,b0,acc[fi][0]); acc[fi][1]=mfma16(a,b1,acc[fi][1]);
      }
    }
  }
  const int plane = mode*8 + h;
  #pragma unroll
  for (int fi=0;fi<2;fi++)
    #pragma unroll
    for (int fj=0;fj<2;fj++)
      #pragma unroll
      for (int r=0;r<4;r++){
        int row = r0 + fi*16 + kg*4 + r;
        int col = c0 + fj*16 + lr;
        Mp[((size_t)plane*BN + b*256 + row)*128 + col] = acc[fi][fj][r];
      }
}

// ---- out = x + sum_p Mp[p]; emit qz = softmax(out) for next iter ------------
__global__ __launch_bounds__(256) void k_redqz(const float* __restrict__ x,
                                               const float* __restrict__ Mp,
                                               float* __restrict__ out,
                                               bf16* __restrict__ qzb){
  const int row = blockIdx.x*4 + (threadIdx.x>>6);
  const int lane = threadIdx.x&63;
  const size_t base = (size_t)row*128;
  float v0 = x[base + lane], v1 = x[base + 64 + lane];
  #pragma unroll
  for (int g=0;g<16;g++){
    v0 += Mp[(size_t)g*524288 + base + lane];
    v1 += Mp[(size_t)g*524288 + base + 64 + lane];
  }
  out[base + lane] = v0; out[base + 64 + lane] = v1;
  float m = fmaxf(v0, v1);
  #pragma unroll
  for (int o=32;o;o>>=1) m = fmaxf(m, __shfl_xor(m, o));
  float e0 = __expf(v0-m), e1 = __expf(v1-m), s = e0+e1;
  #pragma unroll
  for (int o=32;o;o>>=1) s += __shfl_xor(s, o);
  float inv = 1.f/s;
  qzb[base + lane] = f2b(e0*inv); qzb[base + 64 + lane] = f2b(e1*inv);
}

// -----------------------------------------------------------------------------
extern "C" void kernel_launch(void* const* d_in, const int* in_sizes, int n_in,
                              void* d_out, int out_size, void* d_ws, size_t ws_size,
                              hipStream_t stream) {
  (void)in_sizes; (void)n_in; (void)out_size; (void)ws_size;
  const float* x    = (const float*)d_in[0];
  const int*   mask = (const int*)d_in[1];
  const float* tern = (const float*)d_in[2];
  const float* glb  = (const float*)d_in[3];
  float* out = (float*)d_out;

  char* w = (char*)d_ws;
  auto alloc = [&](size_t bytes){ void* p = (void*)w; w += (bytes + 255) & ~(size_t)255; return p; };
  bf16* qzb   = (bf16*) alloc((size_t)BN*128*2);            // 1 MB
  bf16* left  = (bf16*) alloc((size_t)16*BN*128*2);         // 16.8 MB
  bf16* LT2   = (bf16*) alloc((size_t)16*16*128*256*2);     // 16.8 MB
  bf16* RT2   = (bf16*) alloc((size_t)16*16*128*256*2);     // 16.8 MB
  bf16* qh    = (bf16*) alloc((size_t)128*256*SW*2);        // 21 MB
  bf16* qhT2  = (bf16*) alloc((size_t)128*4*256*64*2);      // 16.8 MB
  float* Mp   = (float*)alloc((size_t)16*BN*128*4);         // 33.6 MB
  bf16* TL    = (bf16*) alloc((size_t)16*128*128*2);
  bf16* TR    = (bf16*) alloc((size_t)16*128*128*2);
  bf16* GB    = (bf16*) alloc((size_t)8*64*128*2);
  bf16* GT    = (bf16*) alloc((size_t)8*64*128*2);

  k_prep<<<1024, 256, 0, stream>>>(tern, glb, TL, TR, GB, GT);
  k_softmax_qz<<<1024, 256, 0, stream>>>(x, qzb);

  for (int it = 0; it < 4; ++it){
    k_proj<<<4096, 256, 0, stream>>>(qzb, TL, TR, left, LT2, RT2);
    k_FSM<<<512, 256, 0, stream>>>(qzb, left, GB, mask, qh, qhT2);
    k_M2x<<<2048, 256, 0, stream>>>(qh, qhT2, RT2, LT2, GT, Mp);
    k_redqz<<<1024, 256, 0, stream>>>(x, Mp, out, qzb);
  }
}